// Round 1
// baseline (1105.314 us; speedup 1.0000x reference)
//
#include <hip/hip_runtime.h>
#include <hip/hip_bf16.h>

// ---------------------------------------------------------------------------
// TransformerMoEDecoderLayer: SA -> add+LN -> CA -> add+LN -> MoE top2 -> add+LN
// T=S=1024, B=4, D=1024, H=16, HD=64, F=4096, E=8, N=4096, CAP=1024
// All GEMMs: bf16 MFMA 16x16x32, NT form (B stored [N][K]); fp32 accum.
// ---------------------------------------------------------------------------

typedef __bf16 bf16;
typedef __bf16 bf16x4 __attribute__((ext_vector_type(4)));
typedef __bf16 bf16x8 __attribute__((ext_vector_type(8)));
typedef float  f32x4  __attribute__((ext_vector_type(4)));

static_assert(sizeof(bf16) == 2, "bf16 size");

#define T_ 1024
#define S_ 1024
#define BB 4
#define D_ 1024
#define H_ 16
#define HD_ 64
#define F_ 4096
#define E_ 8
#define N_ 4096
#define CAP_ 1024
#define TS_ 1048576L

// ---------------- workspace layout (bytes) ----------------
// phase-reused; peak ~260.2 MB
static const long OFF_WSAIN  = 0L;                         // bf16 [3072][1024]    6,291,456
static const long OFF_WSAOUT = 6291456L;                   // bf16 [1024][1024]    2,097,152
static const long OFF_WCAIN  = 8388608L;                   // bf16 [3072][1024]    6,291,456
static const long OFF_WCAOUT = 14680064L;                  // bf16 [1024][1024]    2,097,152
static const long OFF_BTGT   = 16777216L;                  // bf16 [4096][1024]    8,388,608  (phase2: xb=bf16(x1))
static const long OFF_BMEM   = 25165824L;                  // bf16 [4096][1024]    8,388,608
static const long OFF_QKV    = 33554432L;                  // bf16 [4096][3072]   25,165,824  (phase2: q_ca + kv_ca; phase3: buf 16,777,216)
static const long OFF_KVCA   = OFF_QKV + 8388608L;         // bf16 [4096][2048]
static const long OFF_VT     = 58720256L;                  // bf16 [64][64][1024]  8,388,608
static const long OFF_AO     = 67108864L;                  // bf16 [4096][1024]    8,388,608
static const long OFF_PROJ   = 75497472L;                  // f32  [4096][1024]   16,777,216  (phase3: eo f32 [8][1024][1024] spans PROJ..X2)
static const long OFF_X1     = 92274688L;                  // f32  [4096][1024]   16,777,216
static const long OFF_X2     = 109051904L;                 // f32  [4096][1024]   16,777,216
static const long OFF_SCORES = 125829120L;                 // bf16 [64][1024][1024] 134,217,728 (phase3: w1t/w2t 67,108,864 + h 67,108,864)
static const long OFF_H      = OFF_SCORES + 67108864L;
static const long OFF_GATE   = 260046848L;                 // small arrays, 9 x 16 KB
static const long OFF_E1   = OFF_GATE;
static const long OFF_E2   = OFF_GATE + 16384L;
static const long OFF_G1   = OFF_GATE + 32768L;
static const long OFF_G2   = OFF_GATE + 49152L;
static const long OFF_D1   = OFF_GATE + 65536L;
static const long OFF_D2   = OFF_GATE + 81920L;
static const long OFF_S1   = OFF_GATE + 98304L;
static const long OFF_S2   = OFF_GATE + 114688L;
static const long OFF_P2T  = OFF_GATE + 131072L;

// ---------------- elementwise fp32 -> bf16 ----------------
__global__ __launch_bounds__(256) void k_f32_to_bf16(const float* __restrict__ in,
                                                     bf16* __restrict__ out, long n4) {
  long i = (long)blockIdx.x * 256 + threadIdx.x;
  if (i >= n4) return;
  float4 v = ((const float4*)in)[i];
  bf16x4 o = {(bf16)v.x, (bf16)v.y, (bf16)v.z, (bf16)v.w};
  ((bf16x4*)out)[i] = o;
}

// ---------------- zero fill (16B granules) ----------------
__global__ __launch_bounds__(256) void k_zero16(float4* __restrict__ p, long n) {
  long i = (long)blockIdx.x * 256 + threadIdx.x;
  if (i < n) p[i] = make_float4(0.f, 0.f, 0.f, 0.f);
}

// ---------------- transpose fp32 [z][R][C] -> bf16 [z][C][R] ----------------
__global__ __launch_bounds__(256) void k_transpose_f32_bf16(const float* __restrict__ in,
                                                            bf16* __restrict__ out, int R, int C) {
  __shared__ float t[64][66];
  int z = blockIdx.z;
  long r0 = (long)blockIdx.y * 64, c0 = (long)blockIdx.x * 64;
  const float* ib = in + (long)z * R * C;
  bf16* ob = out + (long)z * R * C;
  int x = threadIdx.x, y = threadIdx.y;
  #pragma unroll
  for (int i = y; i < 64; i += 4) t[i][x] = ib[(r0 + i) * C + c0 + x];
  __syncthreads();
  #pragma unroll
  for (int i = y; i < 64; i += 4) ob[(c0 + i) * R + r0 + x] = (bf16)t[x][i];
}

// ---------------- extract V^T per head: in rows (stride rs), 64 cols -> out [z][64][1024]
__global__ __launch_bounds__(256) void k_extract_vt(const bf16* __restrict__ in,
                                                    bf16* __restrict__ out, long rs, long sb) {
  __shared__ bf16 t[64][66];
  int z = blockIdx.z;
  long r0 = (long)blockIdx.y * 64;
  const bf16* ib = in + (long)(z >> 4) * sb + (long)(z & 15) * 64;
  bf16* ob = out + (long)z * 64 * 1024;
  int x = threadIdx.x, y = threadIdx.y;
  #pragma unroll
  for (int i = y; i < 64; i += 4) t[i][x] = ib[(r0 + i) * rs + x];
  __syncthreads();
  #pragma unroll
  for (int i = y; i < 64; i += 4) ob[(long)i * 1024 + r0 + x] = t[x][i];
}

// ---------------- generic NT GEMM: C[M,N] = alpha*(A[M,K] @ B[N,K]^T) + bias[N]
// batch via blockIdx.z decomposed as zh=z/zdiv, zl=z%zdiv with per-component strides.
template <int BM, int BN, int WM, int WN, bool RELU, typename OutT>
__global__ __launch_bounds__(256) void k_gemm_nt(
    const bf16* __restrict__ A, const bf16* __restrict__ Bp,
    OutT* __restrict__ C, const float* __restrict__ bias,
    int K, long lda, long ldb, long ldc, float alpha, int zdiv,
    long sA1, long sA0, long sB1, long sB0, long sC1, long sC0,
    long sBias1, long sBias0) {
  constexpr int BK = 32;
  constexpr int WTM = BM / WM, WTN = BN / WN, MR = WTM / 16, NR = WTN / 16;
  __shared__ bf16 sa[BM][BK + 8];
  __shared__ bf16 sb[BN][BK + 8];
  const int z = blockIdx.z, zh = z / zdiv, zl = z - zh * zdiv;
  const bf16* Ab = A + zh * sA1 + zl * sA0 + (long)blockIdx.y * BM * lda;
  const bf16* Bb = Bp + zh * sB1 + zl * sB0 + (long)blockIdx.x * BN * ldb;
  const int tid = threadIdx.x, lane = tid & 63, wid = tid >> 6;
  const int wm = wid / WN, wn = wid % WN;
  f32x4 acc[MR][NR] = {};
  const int rA = wm * WTM + (lane & 15);
  const int rB = wn * WTN + (lane & 15);
  const int kk = (lane >> 4) * 8;
  for (int k0 = 0; k0 < K; k0 += BK) {
    constexpr int CA_ = BM * BK / 8;
    #pragma unroll
    for (int c = tid; c < CA_; c += 256) {
      int row = c >> 2, cc = c & 3;
      *(bf16x8*)&sa[row][cc * 8] = *(const bf16x8*)&Ab[(long)row * lda + k0 + cc * 8];
    }
    constexpr int CB_ = BN * BK / 8;
    #pragma unroll
    for (int c = tid; c < CB_; c += 256) {
      int row = c >> 2, cc = c & 3;
      *(bf16x8*)&sb[row][cc * 8] = *(const bf16x8*)&Bb[(long)row * ldb + k0 + cc * 8];
    }
    __syncthreads();
    bf16x8 af[MR], bfr[NR];
    #pragma unroll
    for (int mi = 0; mi < MR; mi++) af[mi] = *(const bf16x8*)&sa[rA + mi * 16][kk];
    #pragma unroll
    for (int ni = 0; ni < NR; ni++) bfr[ni] = *(const bf16x8*)&sb[rB + ni * 16][kk];
    #pragma unroll
    for (int mi = 0; mi < MR; mi++)
      #pragma unroll
      for (int ni = 0; ni < NR; ni++)
        acc[mi][ni] = __builtin_amdgcn_mfma_f32_16x16x32_bf16(af[mi], bfr[ni], acc[mi][ni], 0, 0, 0);
    __syncthreads();
  }
  OutT* Cb = C + zh * sC1 + zl * sC0;
  const float* biasb = bias ? (bias + zh * sBias1 + zl * sBias0) : nullptr;
  const long rowBase = (long)blockIdx.y * BM + wm * WTM + ((lane >> 4) * 4);
  const long colBase = (long)blockIdx.x * BN + wn * WTN + (lane & 15);
  #pragma unroll
  for (int mi = 0; mi < MR; mi++) {
    #pragma unroll
    for (int ni = 0; ni < NR; ni++) {
      long col = colBase + ni * 16;
      float bv = biasb ? biasb[col] : 0.f;
      #pragma unroll
      for (int r = 0; r < 4; r++) {
        long row = rowBase + mi * 16 + r;
        float v = acc[mi][ni][r] * alpha + bv;
        if (RELU) v = fmaxf(v, 0.f);
        Cb[row * ldc + col] = (OutT)v;
      }
    }
  }
}

// ---------------- row softmax (rows of 1024 bf16, in place) ----------------
__global__ __launch_bounds__(256) void k_softmax_row(bf16* __restrict__ s) {
  long row = blockIdx.x;
  bf16* p = s + row * 1024;
  int tid = threadIdx.x;
  bf16x4 vv = ((bf16x4*)p)[tid];
  float v[4];
  float mx = -INFINITY;
  #pragma unroll
  for (int i = 0; i < 4; i++) { v[i] = (float)vv[i]; mx = fmaxf(mx, v[i]); }
  #pragma unroll
  for (int o = 32; o; o >>= 1) mx = fmaxf(mx, __shfl_xor(mx, o));
  __shared__ float redm[4], reds[4];
  int wid = tid >> 6;
  if ((tid & 63) == 0) redm[wid] = mx;
  __syncthreads();
  mx = fmaxf(fmaxf(redm[0], redm[1]), fmaxf(redm[2], redm[3]));
  float sum = 0.f;
  #pragma unroll
  for (int i = 0; i < 4; i++) { v[i] = __expf(v[i] - mx); sum += v[i]; }
  #pragma unroll
  for (int o = 32; o; o >>= 1) sum += __shfl_xor(sum, o);
  if ((tid & 63) == 0) reds[wid] = sum;
  __syncthreads();
  sum = reds[0] + reds[1] + reds[2] + reds[3];
  float inv = 1.f / sum;
  bf16x4 ov;
  #pragma unroll
  for (int i = 0; i < 4; i++) ov[i] = (bf16)(v[i] * inv);
  ((bf16x4*)p)[tid] = ov;
}

// ---------------- residual add + LayerNorm (row=1024), optional bf16 copy ----
__global__ __launch_bounds__(256) void k_add_ln(const float* __restrict__ a, const float* __restrict__ b,
                                                const float* __restrict__ g, const float* __restrict__ be,
                                                float* __restrict__ out, bf16* __restrict__ outb) {
  long row = blockIdx.x;
  int tid = threadIdx.x;
  const float* pa = a + row * 1024;
  const float* pb = b + row * 1024;
  float v[4];
  float s = 0.f, sq = 0.f;
  #pragma unroll
  for (int i = 0; i < 4; i++) {
    int c = tid + i * 256;
    float x = pa[c] + pb[c];
    v[i] = x; s += x; sq += x * x;
  }
  #pragma unroll
  for (int o = 32; o; o >>= 1) { s += __shfl_xor(s, o); sq += __shfl_xor(sq, o); }
  __shared__ float r1[4], r2[4];
  int wid = tid >> 6;
  if ((tid & 63) == 0) { r1[wid] = s; r2[wid] = sq; }
  __syncthreads();
  s = r1[0] + r1[1] + r1[2] + r1[3];
  sq = r2[0] + r2[1] + r2[2] + r2[3];
  float mu = s * (1.f / 1024.f);
  float var = sq * (1.f / 1024.f) - mu * mu;
  float rstd = rsqrtf(var + 1e-5f);
  #pragma unroll
  for (int i = 0; i < 4; i++) {
    int c = tid + i * 256;
    float y = (v[i] - mu) * rstd * g[c] + be[c];
    out[row * 1024 + c] = y;
    if (outb) outb[row * 1024 + c] = (bf16)y;
  }
}

// ---------------- MoE gating: logits, softmax, top-2 (fp32, wave per token) ----
__global__ __launch_bounds__(256) void k_gate(const float* __restrict__ x, const float* __restrict__ wg,
                                              int* __restrict__ e1, int* __restrict__ e2,
                                              float* __restrict__ g1, float* __restrict__ g2) {
  int n = blockIdx.x * 4 + (threadIdx.x >> 6);
  int lane = threadIdx.x & 63;
  const float* xr = x + (long)n * 1024;
  float acc[8] = {0.f, 0.f, 0.f, 0.f, 0.f, 0.f, 0.f, 0.f};
  for (int i = 0; i < 16; i++) {
    float xv = xr[i * 64 + lane];
    const float* wr = wg + (long)(i * 64 + lane) * 8;
    #pragma unroll
    for (int e = 0; e < 8; e++) acc[e] += xv * wr[e];
  }
  #pragma unroll
  for (int e = 0; e < 8; e++)
    #pragma unroll
    for (int o = 32; o; o >>= 1) acc[e] += __shfl_xor(acc[e], o);
  if (lane == 0) {
    int i1 = 0; float b1v = acc[0];
    #pragma unroll
    for (int e = 1; e < 8; e++) if (acc[e] > b1v) { b1v = acc[e]; i1 = e; }
    int i2 = -1; float b2v = -INFINITY;
    #pragma unroll
    for (int e = 0; e < 8; e++) if (e != i1 && acc[e] > b2v) { b2v = acc[e]; i2 = e; }
    float den = 0.f;
    #pragma unroll
    for (int e = 0; e < 8; e++) den += __expf(acc[e] - b1v);
    float gg1 = 1.f / den;                 // exp(0)/den
    float gg2 = __expf(b2v - b1v) / den;
    float dn = gg1 + gg2 + 1e-9f;
    e1[n] = i1; e2[n] = i2; g1[n] = gg1 / dn; g2[n] = gg2 / dn;
  }
}

// ---------------- capacity positions (ordered cumsum semantics), single wave ----
__global__ __launch_bounds__(64) void k_positions(const int* __restrict__ e1, const int* __restrict__ e2,
                                                  const float* __restrict__ g1, const float* __restrict__ g2,
                                                  int* __restrict__ d1, int* __restrict__ d2,
                                                  float* __restrict__ s1, float* __restrict__ s2,
                                                  int* __restrict__ p2t) {
  const int lane = threadIdx.x;
  int base1[8] = {0, 0, 0, 0, 0, 0, 0, 0};
  int base2[8] = {0, 0, 0, 0, 0, 0, 0, 0};
  const unsigned long long lt = (1ull << lane) - 1ull;
  int na = e1[lane], nb = e2[lane];
  for (int c = 0; c < 64; c++) {
    int a = na, b = nb;
    if (c < 63) { na = e1[(c + 1) * 64 + lane]; nb = e2[(c + 1) * 64 + lane]; }
    int n = c * 64 + lane;
    int pa = 0, pb = 0;
    #pragma unroll
    for (int e = 0; e < 8; e++) {
      unsigned long long ba = __ballot(a == e);
      unsigned long long bb = __ballot(b == e);
      if (a == e) pa = base1[e] + __popcll(ba & lt);
      if (b == e) pb = base2[e] + __popcll(bb & lt);
      base1[e] += __popcll(ba);
      base2[e] += __popcll(bb);
    }
    d1[n] = a * CAP_ + (pa < CAP_ ? pa : CAP_ - 1);
    s1[n] = (pa < CAP_) ? g1[n] : 0.f;
    p2t[n] = pb;
  }
  __shared__ int c1[8];
  if (lane == 0) {
    c1[0] = base1[0]; c1[1] = base1[1]; c1[2] = base1[2]; c1[3] = base1[3];
    c1[4] = base1[4]; c1[5] = base1[5]; c1[6] = base1[6]; c1[7] = base1[7];
  }
  __syncthreads();
  for (int c = 0; c < 64; c++) {
    int n = c * 64 + lane;
    int b = e2[n];
    int pb = p2t[n] + c1[b];
    d2[n] = b * CAP_ + (pb < CAP_ ? pb : CAP_ - 1);
    s2[n] = (pb < CAP_) ? g2[n] : 0.f;
  }
}

// ---------------- scatter tokens into expert buffers (bf16) ----------------
__global__ __launch_bounds__(256) void k_scatter(const float* __restrict__ x, const int* __restrict__ d1,
                                                 const int* __restrict__ d2, const float* __restrict__ s1,
                                                 const float* __restrict__ s2, bf16* __restrict__ buf) {
  int n = blockIdx.x;
  int tid = threadIdx.x;
  const float* xr = x + (long)n * 1024;
  float v[4];
  #pragma unroll
  for (int i = 0; i < 4; i++) v[i] = xr[tid + i * 256];
  if (s1[n] != 0.f) {
    bf16* o = buf + (long)d1[n] * 1024;
    #pragma unroll
    for (int i = 0; i < 4; i++) o[tid + i * 256] = (bf16)v[i];
  }
  if (s2[n] != 0.f) {
    bf16* o = buf + (long)d2[n] * 1024;
    #pragma unroll
    for (int i = 0; i < 4; i++) o[tid + i * 256] = (bf16)v[i];
  }
}

// ---------------- gather expert outputs + residual + final LN -> d_out ------
__global__ __launch_bounds__(256) void k_gather_ln(const float* __restrict__ x, const float* __restrict__ eo,
                                                   const int* __restrict__ d1, const int* __restrict__ d2,
                                                   const float* __restrict__ s1, const float* __restrict__ s2,
                                                   const float* __restrict__ g, const float* __restrict__ be,
                                                   float* __restrict__ out) {
  long n = blockIdx.x;
  int tid = threadIdx.x;
  float a1 = s1[n], a2 = s2[n];
  const float* r1p = eo + (long)d1[n] * 1024;
  const float* r2p = eo + (long)d2[n] * 1024;
  const float* xr = x + n * 1024;
  float v[4];
  float s = 0.f, sq = 0.f;
  #pragma unroll
  for (int i = 0; i < 4; i++) {
    int c = tid + i * 256;
    float y = xr[c] + a1 * r1p[c] + a2 * r2p[c];
    v[i] = y; s += y; sq += y * y;
  }
  #pragma unroll
  for (int o = 32; o; o >>= 1) { s += __shfl_xor(s, o); sq += __shfl_xor(sq, o); }
  __shared__ float r1[4], r2[4];
  int wid = tid >> 6;
  if ((tid & 63) == 0) { r1[wid] = s; r2[wid] = sq; }
  __syncthreads();
  s = r1[0] + r1[1] + r1[2] + r1[3];
  sq = r2[0] + r2[1] + r2[2] + r2[3];
  float mu = s * (1.f / 1024.f);
  float var = sq * (1.f / 1024.f) - mu * mu;
  float rstd = rsqrtf(var + 1e-5f);
  #pragma unroll
  for (int i = 0; i < 4; i++) {
    int c = tid + i * 256;
    out[n * 1024 + c] = (v[i] - mu) * rstd * g[c] + be[c];
  }
}

// ---------------------------------------------------------------------------
extern "C" void kernel_launch(void* const* d_in, const int* in_sizes, int n_in,
                              void* d_out, int out_size, void* d_ws, size_t ws_size,
                              hipStream_t stream) {
  const float* tgt      = (const float*)d_in[0];
  const float* memory   = (const float*)d_in[1];
  const float* sa_in_w  = (const float*)d_in[2];
  const float* sa_in_b  = (const float*)d_in[3];
  const float* sa_out_w = (const float*)d_in[4];
  const float* sa_out_b = (const float*)d_in[5];
  const float* ca_in_w  = (const float*)d_in[6];
  const float* ca_in_b  = (const float*)d_in[7];
  const float* ca_out_w = (const float*)d_in[8];
  const float* ca_out_b = (const float*)d_in[9];
  const float* ln1_g    = (const float*)d_in[10];
  const float* ln1_b    = (const float*)d_in[11];
  const float* ln2_g    = (const float*)d_in[12];
  const float* ln2_b    = (const float*)d_in[13];
  const float* ln3_g    = (const float*)d_in[14];
  const float* ln3_b    = (const float*)d_in[15];
  const float* wg       = (const float*)d_in[16];
  const float* w1       = (const float*)d_in[17];
  const float* b1       = (const float*)d_in[18];
  const float* w2       = (const float*)d_in[19];
  const float* b2       = (const float*)d_in[20];

  char* ws = (char*)d_ws;
  auto B16 = [&](long o) { return (bf16*)(ws + o); };
  auto F32 = [&](long o) { return (float*)(ws + o); };
  auto I32 = [&](long o) { return (int*)(ws + o); };

  const dim3 blk256(256), blkT(64, 4);

  // ---- phase 0: conversions to bf16
  k_f32_to_bf16<<<3072, blk256, 0, stream>>>(sa_in_w, B16(OFF_WSAIN), 3072L * 1024 / 4);
  k_f32_to_bf16<<<1024, blk256, 0, stream>>>(sa_out_w, B16(OFF_WSAOUT), 1024L * 1024 / 4);
  k_f32_to_bf16<<<3072, blk256, 0, stream>>>(ca_in_w, B16(OFF_WCAIN), 3072L * 1024 / 4);
  k_f32_to_bf16<<<1024, blk256, 0, stream>>>(ca_out_w, B16(OFF_WCAOUT), 1024L * 1024 / 4);
  k_f32_to_bf16<<<4096, blk256, 0, stream>>>(tgt, B16(OFF_BTGT), 4096L * 1024 / 4);
  k_f32_to_bf16<<<4096, blk256, 0, stream>>>(memory, B16(OFF_BMEM), 4096L * 1024 / 4);

  // ---- phase 1: self-attention
  // qkv = tgt @ sa_in_w^T + b : [4096,3072]
  k_gemm_nt<128, 128, 2, 2, false, bf16><<<dim3(24, 32, 1), blk256, 0, stream>>>(
      B16(OFF_BTGT), B16(OFF_WSAIN), B16(OFF_QKV), sa_in_b,
      1024, 1024, 1024, 3072, 1.f, 1, 0, 0, 0, 0, 0, 0, 0, 0);
  // v^T per head
  k_extract_vt<<<dim3(1, 16, 64), blkT, 0, stream>>>(B16(OFF_QKV) + 2048, B16(OFF_VT), 12288, 3072);
  // scores = q @ k^T / 8 : per head [1024,1024]
  k_gemm_nt<128, 128, 2, 2, false, bf16><<<dim3(8, 8, 64), blk256, 0, stream>>>(
      B16(OFF_QKV), B16(OFF_QKV) + 1024, B16(OFF_SCORES), nullptr,
      64, 12288, 12288, 1024, 0.125f, 16,
      3072, 64, 3072, 64, 16L * TS_, TS_, 0, 0);
  k_softmax_row<<<65536, blk256, 0, stream>>>(B16(OFF_SCORES));
  // o = attn @ v : per head [1024,64] -> ao[t*4+b][h*64+hd]
  k_gemm_nt<128, 64, 4, 1, false, bf16><<<dim3(1, 8, 64), blk256, 0, stream>>>(
      B16(OFF_SCORES), B16(OFF_VT), B16(OFF_AO), nullptr,
      1024, 1024, 1024, 4096, 1.f, 16,
      16L * TS_, TS_, 16L * 65536, 65536, 1024, 64, 0, 0);
  // out proj
  k_gemm_nt<128, 128, 2, 2, false, float><<<dim3(8, 32, 1), blk256, 0, stream>>>(
      B16(OFF_AO), B16(OFF_WSAOUT), F32(OFF_PROJ), sa_out_b,
      1024, 1024, 1024, 1024, 1.f, 1, 0, 0, 0, 0, 0, 0, 0, 0);
  // x1 = LN(tgt + proj); also bf16 copy into OFF_BTGT (b_tgt now dead)
  k_add_ln<<<4096, blk256, 0, stream>>>(tgt, F32(OFF_PROJ), ln1_g, ln1_b, F32(OFF_X1), B16(OFF_BTGT));

  // ---- phase 2: cross-attention
  k_gemm_nt<128, 128, 2, 2, false, bf16><<<dim3(8, 32, 1), blk256, 0, stream>>>(
      B16(OFF_BTGT), B16(OFF_WCAIN), B16(OFF_QKV), ca_in_b,
      1024, 1024, 1024, 1024, 1.f, 1, 0, 0, 0, 0, 0, 0, 0, 0);
  k_gemm_nt<128, 128, 2, 2, false, bf16><<<dim3(16, 32, 1), blk256, 0, stream>>>(
      B16(OFF_BMEM), B16(OFF_WCAIN) + 1024L * 1024, B16(OFF_KVCA), ca_in_b + 1024,
      1024, 1024, 1024, 2048, 1.f, 1, 0, 0, 0, 0, 0, 0, 0, 0);
  k_extract_vt<<<dim3(1, 16, 64), blkT, 0, stream>>>(B16(OFF_KVCA) + 1024, B16(OFF_VT), 8192, 2048);
  k_gemm_nt<128, 128, 2, 2, false, bf16><<<dim3(8, 8, 64), blk256, 0, stream>>>(
      B16(OFF_QKV), B16(OFF_KVCA), B16(OFF_SCORES), nullptr,
      64, 4096, 8192, 1024, 0.125f, 16,
      1024, 64, 2048, 64, 16L * TS_, TS_, 0, 0);
  k_softmax_row<<<65536, blk256, 0, stream>>>(B16(OFF_SCORES));
  k_gemm_nt<128, 64, 4, 1, false, bf16><<<dim3(1, 8, 64), blk256, 0, stream>>>(
      B16(OFF_SCORES), B16(OFF_VT), B16(OFF_AO), nullptr,
      1024, 1024, 1024, 4096, 1.f, 16,
      16L * TS_, TS_, 16L * 65536, 65536, 1024, 64, 0, 0);
  k_gemm_nt<128, 128, 2, 2, false, float><<<dim3(8, 32, 1), blk256, 0, stream>>>(
      B16(OFF_AO), B16(OFF_WCAOUT), F32(OFF_PROJ), ca_out_b,
      1024, 1024, 1024, 1024, 1.f, 1, 0, 0, 0, 0, 0, 0, 0, 0);
  k_add_ln<<<4096, blk256, 0, stream>>>(F32(OFF_X1), F32(OFF_PROJ), ln2_g, ln2_b, F32(OFF_X2), (bf16*)nullptr);

  // ---- phase 3: MoE
  k_gate<<<1024, blk256, 0, stream>>>(F32(OFF_X2), wg, I32(OFF_E1), I32(OFF_E2), F32(OFF_G1), F32(OFF_G2));
  k_positions<<<1, 64, 0, stream>>>(I32(OFF_E1), I32(OFF_E2), F32(OFF_G1), F32(OFF_G2),
                                    I32(OFF_D1), I32(OFF_D2), F32(OFF_S1), F32(OFF_S2), I32(OFF_P2T));
  // zero expert buffers (buf reuses OFF_QKV region, 16 MB)
  k_zero16<<<4096, blk256, 0, stream>>>((float4*)B16(OFF_QKV), 1048576L);
  k_scatter<<<4096, blk256, 0, stream>>>(F32(OFF_X2), I32(OFF_D1), I32(OFF_D2),
                                         F32(OFF_S1), F32(OFF_S2), B16(OFF_QKV));
  // w1t[e] = w1[e]^T : [F][D] bf16 (into scores region)
  k_transpose_f32_bf16<<<dim3(64, 16, 8), blkT, 0, stream>>>(w1, B16(OFF_SCORES), 1024, 4096);
  // h = relu(buf @ w1t^T + b1) : [E][1024][4096] bf16
  k_gemm_nt<128, 128, 2, 2, true, bf16><<<dim3(32, 8, 8), blk256, 0, stream>>>(
      B16(OFF_QKV), B16(OFF_SCORES), B16(OFF_H), b1,
      1024, 1024, 1024, 4096, 1.f, 1,
      1048576, 0, 4194304, 0, 4194304, 0, 4096, 0);
  // w2t[e] = w2[e]^T : [D][F] bf16 (overwrite w1t)
  k_transpose_f32_bf16<<<dim3(16, 64, 8), blkT, 0, stream>>>(w2, B16(OFF_SCORES), 4096, 1024);
  // eo = h @ w2t^T + b2 : [E][1024][1024] f32 (into PROJ..X2 region)
  k_gemm_nt<128, 128, 2, 2, false, float><<<dim3(8, 8, 8), blk256, 0, stream>>>(
      B16(OFF_H), B16(OFF_SCORES), F32(OFF_PROJ), b2,
      4096, 4096, 4096, 1024, 1.f, 1,
      4194304, 0, 4194304, 0, 1048576, 0, 1024, 0);
  // gather + residual + LN3 -> out
  k_gather_ln<<<4096, blk256, 0, stream>>>(F32(OFF_X2), F32(OFF_PROJ), I32(OFF_D1), I32(OFF_D2),
                                           F32(OFF_S1), F32(OFF_S2), ln3_g, ln3_b, (float*)d_out);

  (void)in_sizes; (void)n_in; (void)out_size; (void)ws_size;
}

// Round 2
// 905.556 us; speedup vs baseline: 1.2206x; 1.2206x over previous
//
#include <hip/hip_runtime.h>
#include <hip/hip_bf16.h>

// ---------------------------------------------------------------------------
// TransformerMoEDecoderLayer: SA -> add+LN -> CA -> add+LN -> MoE top2 -> add+LN
// T=S=1024, B=4, D=1024, H=16, HD=64, F=4096, E=8, N=4096, CAP=1024
// All GEMMs: bf16 MFMA 16x16x32, NT form (B stored [N][K]); fp32 accum.
// Round 2: m97-structure GEMM (global_load_lds width=16, linear LDS).
// ---------------------------------------------------------------------------

typedef __bf16 bf16;
typedef __bf16 bf16x4 __attribute__((ext_vector_type(4)));
typedef __bf16 bf16x8 __attribute__((ext_vector_type(8)));
typedef float  f32x4  __attribute__((ext_vector_type(4)));

static_assert(sizeof(bf16) == 2, "bf16 size");

#define T_ 1024
#define S_ 1024
#define BB 4
#define D_ 1024
#define H_ 16
#define HD_ 64
#define F_ 4096
#define E_ 8
#define N_ 4096
#define CAP_ 1024
#define TS_ 1048576L

// global -> LDS direct copy, 16B per lane; LDS dest = base + lane*16 (linear)
#define GLOAD16(g, l)                                                  \
  __builtin_amdgcn_global_load_lds(                                    \
      (const __attribute__((address_space(1))) unsigned int*)(g),      \
      (__attribute__((address_space(3))) unsigned int*)(l), 16, 0, 0)

// ---------------- workspace layout (bytes) ----------------
static const long OFF_WSAIN  = 0L;                         // bf16 [3072][1024]
static const long OFF_WSAOUT = 6291456L;                   // bf16 [1024][1024]
static const long OFF_WCAIN  = 8388608L;                   // bf16 [3072][1024]
static const long OFF_WCAOUT = 14680064L;                  // bf16 [1024][1024]
static const long OFF_BTGT   = 16777216L;                  // bf16 [4096][1024]
static const long OFF_BMEM   = 25165824L;                  // bf16 [4096][1024]
static const long OFF_QKV    = 33554432L;                  // bf16 [4096][3072] (phase3: expert buf)
static const long OFF_KVCA   = OFF_QKV + 8388608L;         // bf16 [4096][2048]
static const long OFF_VT     = 58720256L;                  // bf16 [64][64][1024]
static const long OFF_AO     = 67108864L;                  // bf16 [4096][1024]
static const long OFF_PROJ   = 75497472L;                  // f32  [4096][1024] (phase3: eo f32 [8][1024][1024])
static const long OFF_X1     = 92274688L;                  // f32  [4096][1024]
static const long OFF_X2     = 109051904L;                 // f32  [4096][1024]
static const long OFF_SCORES = 125829120L;                 // bf16 [64][1024][1024] (phase3: w1t/w2t + h)
static const long OFF_H      = OFF_SCORES + 67108864L;
static const long OFF_GATE   = 260046848L;
static const long OFF_E1   = OFF_GATE;
static const long OFF_E2   = OFF_GATE + 16384L;
static const long OFF_G1   = OFF_GATE + 32768L;
static const long OFF_G2   = OFF_GATE + 49152L;
static const long OFF_D1   = OFF_GATE + 65536L;
static const long OFF_D2   = OFF_GATE + 81920L;
static const long OFF_S1   = OFF_GATE + 98304L;
static const long OFF_S2   = OFF_GATE + 114688L;
static const long OFF_P2T  = OFF_GATE + 131072L;

// ---------------- elementwise fp32 -> bf16 ----------------
__global__ __launch_bounds__(256) void k_f32_to_bf16(const float* __restrict__ in,
                                                     bf16* __restrict__ out, long n4) {
  long i = (long)blockIdx.x * 256 + threadIdx.x;
  if (i >= n4) return;
  float4 v = ((const float4*)in)[i];
  bf16x4 o = {(bf16)v.x, (bf16)v.y, (bf16)v.z, (bf16)v.w};
  ((bf16x4*)out)[i] = o;
}

// ---------------- zero fill (16B granules) ----------------
__global__ __launch_bounds__(256) void k_zero16(float4* __restrict__ p, long n) {
  long i = (long)blockIdx.x * 256 + threadIdx.x;
  if (i < n) p[i] = make_float4(0.f, 0.f, 0.f, 0.f);
}

// ---------------- transpose fp32 [z][R][C] -> bf16 [z][C][R] ----------------
__global__ __launch_bounds__(256) void k_transpose_f32_bf16(const float* __restrict__ in,
                                                            bf16* __restrict__ out, int R, int C) {
  __shared__ float t[64][66];
  int z = blockIdx.z;
  long r0 = (long)blockIdx.y * 64, c0 = (long)blockIdx.x * 64;
  const float* ib = in + (long)z * R * C;
  bf16* ob = out + (long)z * R * C;
  int x = threadIdx.x, y = threadIdx.y;
  #pragma unroll
  for (int i = y; i < 64; i += 4) t[i][x] = ib[(r0 + i) * C + c0 + x];
  __syncthreads();
  #pragma unroll
  for (int i = y; i < 64; i += 4) ob[(c0 + i) * R + r0 + x] = (bf16)t[x][i];
}

// ---------------- extract V^T per head ----------------
__global__ __launch_bounds__(256) void k_extract_vt(const bf16* __restrict__ in,
                                                    bf16* __restrict__ out, long rs, long sb) {
  __shared__ bf16 t[64][66];
  int z = blockIdx.z;
  long r0 = (long)blockIdx.y * 64;
  const bf16* ib = in + (long)(z >> 4) * sb + (long)(z & 15) * 64;
  bf16* ob = out + (long)z * 64 * 1024;
  int x = threadIdx.x, y = threadIdx.y;
  #pragma unroll
  for (int i = y; i < 64; i += 4) t[i][x] = ib[(r0 + i) * rs + x];
  __syncthreads();
  #pragma unroll
  for (int i = y; i < 64; i += 4) ob[(long)i * 1024 + r0 + x] = t[x][i];
}

// ---------------- generic NT GEMM (m97 structure) ----------------
// C[M,N] = alpha*(A[M,K] @ B[N,K]^T) + bias[N]; batch via blockIdx.z.
// LDS tiles are LINEAR [rows][32] bf16 (64B rows) staged by global_load_lds;
// the lane->address order of the staging loop IS the LDS layout (m104/m173).
template <int BM, int BN, int WM, int WN, bool RELU, typename OutT>
__global__ __launch_bounds__(256) void k_gemm_nt(
    const bf16* __restrict__ A, const bf16* __restrict__ Bp,
    OutT* __restrict__ C, const float* __restrict__ bias,
    int K, long lda, long ldb, long ldc, float alpha, int zdiv,
    long sA1, long sA0, long sB1, long sB0, long sC1, long sC0,
    long sBias1, long sBias0) {
  constexpr int BK = 32;
  constexpr int WTM = BM / WM, WTN = BN / WN, MR = WTM / 16, NR = WTN / 16;
  constexpr int AISS = BM * BK / 2048;   // 256 lanes * 8 elems per issue
  constexpr int BISS = BN * BK / 2048;
  __shared__ bf16 sa[BM * BK];
  __shared__ bf16 sb[BN * BK];
  const int z = blockIdx.z, zh = z / zdiv, zl = z - zh * zdiv;
  const bf16* Ab = A + zh * sA1 + zl * sA0 + (long)blockIdx.y * BM * lda;
  const bf16* Bb = Bp + zh * sB1 + zl * sB0 + (long)blockIdx.x * BN * ldb;
  const int tid = threadIdx.x, lane = tid & 63, wid = tid >> 6;
  const int wm = wid / WN, wn = wid % WN;

  // staging addresses: thread tid covers elems [i*2048 + tid*8, +8)
  const int srow = tid >> 2;              // 0..63
  const int scol = (tid & 3) * 8;         // 0,8,16,24
  const bf16* aptr[AISS];
  bf16* aldst[AISS];
  #pragma unroll
  for (int i = 0; i < AISS; i++) {
    aptr[i] = Ab + (long)(srow + i * 64) * lda + scol;
    aldst[i] = &sa[i * 2048 + (wid << 9)];
  }
  const bf16* bptr[BISS];
  bf16* bldst[BISS];
  #pragma unroll
  for (int i = 0; i < BISS; i++) {
    bptr[i] = Bb + (long)(srow + i * 64) * ldb + scol;
    bldst[i] = &sb[i * 2048 + (wid << 9)];
  }

  f32x4 acc[MR][NR] = {};
  const int rA = wm * WTM + (lane & 15);
  const int rB = wn * WTN + (lane & 15);
  const int kk = (lane >> 4) * 8;

  for (int k0 = 0; k0 < K; k0 += BK) {
    #pragma unroll
    for (int i = 0; i < AISS; i++) GLOAD16(aptr[i] + k0, aldst[i]);
    #pragma unroll
    for (int i = 0; i < BISS; i++) GLOAD16(bptr[i] + k0, bldst[i]);
    __syncthreads();   // compiler drains vmcnt before s_barrier
    bf16x8 af[MR], bfr[NR];
    #pragma unroll
    for (int mi = 0; mi < MR; mi++) af[mi] = *(const bf16x8*)&sa[(rA + mi * 16) * BK + kk];
    #pragma unroll
    for (int ni = 0; ni < NR; ni++) bfr[ni] = *(const bf16x8*)&sb[(rB + ni * 16) * BK + kk];
    #pragma unroll
    for (int mi = 0; mi < MR; mi++)
      #pragma unroll
      for (int ni = 0; ni < NR; ni++)
        acc[mi][ni] = __builtin_amdgcn_mfma_f32_16x16x32_bf16(af[mi], bfr[ni], acc[mi][ni], 0, 0, 0);
    __syncthreads();
  }
  OutT* Cb = C + zh * sC1 + zl * sC0;
  const float* biasb = bias ? (bias + zh * sBias1 + zl * sBias0) : nullptr;
  const long rowBase = (long)blockIdx.y * BM + wm * WTM + ((lane >> 4) * 4);
  const long colBase = (long)blockIdx.x * BN + wn * WTN + (lane & 15);
  #pragma unroll
  for (int mi = 0; mi < MR; mi++) {
    #pragma unroll
    for (int ni = 0; ni < NR; ni++) {
      long col = colBase + ni * 16;
      float bv = biasb ? biasb[col] : 0.f;
      #pragma unroll
      for (int r = 0; r < 4; r++) {
        long row = rowBase + mi * 16 + r;
        float v = acc[mi][ni][r] * alpha + bv;
        if (RELU) v = fmaxf(v, 0.f);
        Cb[row * ldc + col] = (OutT)v;
      }
    }
  }
}

// ---------------- row softmax (rows of 1024 bf16, in place) ----------------
__global__ __launch_bounds__(256) void k_softmax_row(bf16* __restrict__ s) {
  long row = blockIdx.x;
  bf16* p = s + row * 1024;
  int tid = threadIdx.x;
  bf16x4 vv = ((bf16x4*)p)[tid];
  float v[4];
  float mx = -INFINITY;
  #pragma unroll
  for (int i = 0; i < 4; i++) { v[i] = (float)vv[i]; mx = fmaxf(mx, v[i]); }
  #pragma unroll
  for (int o = 32; o; o >>= 1) mx = fmaxf(mx, __shfl_xor(mx, o));
  __shared__ float redm[4], reds[4];
  int wid = tid >> 6;
  if ((tid & 63) == 0) redm[wid] = mx;
  __syncthreads();
  mx = fmaxf(fmaxf(redm[0], redm[1]), fmaxf(redm[2], redm[3]));
  float sum = 0.f;
  #pragma unroll
  for (int i = 0; i < 4; i++) { v[i] = __expf(v[i] - mx); sum += v[i]; }
  #pragma unroll
  for (int o = 32; o; o >>= 1) sum += __shfl_xor(sum, o);
  if ((tid & 63) == 0) reds[wid] = sum;
  __syncthreads();
  sum = reds[0] + reds[1] + reds[2] + reds[3];
  float inv = 1.f / sum;
  bf16x4 ov;
  #pragma unroll
  for (int i = 0; i < 4; i++) ov[i] = (bf16)(v[i] * inv);
  ((bf16x4*)p)[tid] = ov;
}

// ---------------- residual add + LayerNorm ----------------
__global__ __launch_bounds__(256) void k_add_ln(const float* __restrict__ a, const float* __restrict__ b,
                                                const float* __restrict__ g, const float* __restrict__ be,
                                                float* __restrict__ out, bf16* __restrict__ outb) {
  long row = blockIdx.x;
  int tid = threadIdx.x;
  const float* pa = a + row * 1024;
  const float* pb = b + row * 1024;
  float v[4];
  float s = 0.f, sq = 0.f;
  #pragma unroll
  for (int i = 0; i < 4; i++) {
    int c = tid + i * 256;
    float x = pa[c] + pb[c];
    v[i] = x; s += x; sq += x * x;
  }
  #pragma unroll
  for (int o = 32; o; o >>= 1) { s += __shfl_xor(s, o); sq += __shfl_xor(sq, o); }
  __shared__ float r1[4], r2[4];
  int wid = tid >> 6;
  if ((tid & 63) == 0) { r1[wid] = s; r2[wid] = sq; }
  __syncthreads();
  s = r1[0] + r1[1] + r1[2] + r1[3];
  sq = r2[0] + r2[1] + r2[2] + r2[3];
  float mu = s * (1.f / 1024.f);
  float var = sq * (1.f / 1024.f) - mu * mu;
  float rstd = rsqrtf(var + 1e-5f);
  #pragma unroll
  for (int i = 0; i < 4; i++) {
    int c = tid + i * 256;
    float y = (v[i] - mu) * rstd * g[c] + be[c];
    out[row * 1024 + c] = y;
    if (outb) outb[row * 1024 + c] = (bf16)y;
  }
}

// ---------------- MoE gating ----------------
__global__ __launch_bounds__(256) void k_gate(const float* __restrict__ x, const float* __restrict__ wg,
                                              int* __restrict__ e1, int* __restrict__ e2,
                                              float* __restrict__ g1, float* __restrict__ g2) {
  int n = blockIdx.x * 4 + (threadIdx.x >> 6);
  int lane = threadIdx.x & 63;
  const float* xr = x + (long)n * 1024;
  float acc[8] = {0.f, 0.f, 0.f, 0.f, 0.f, 0.f, 0.f, 0.f};
  for (int i = 0; i < 16; i++) {
    float xv = xr[i * 64 + lane];
    const float* wr = wg + (long)(i * 64 + lane) * 8;
    #pragma unroll
    for (int e = 0; e < 8; e++) acc[e] += xv * wr[e];
  }
  #pragma unroll
  for (int e = 0; e < 8; e++)
    #pragma unroll
    for (int o = 32; o; o >>= 1) acc[e] += __shfl_xor(acc[e], o);
  if (lane == 0) {
    int i1 = 0; float b1v = acc[0];
    #pragma unroll
    for (int e = 1; e < 8; e++) if (acc[e] > b1v) { b1v = acc[e]; i1 = e; }
    int i2 = -1; float b2v = -INFINITY;
    #pragma unroll
    for (int e = 0; e < 8; e++) if (e != i1 && acc[e] > b2v) { b2v = acc[e]; i2 = e; }
    float den = 0.f;
    #pragma unroll
    for (int e = 0; e < 8; e++) den += __expf(acc[e] - b1v);
    float gg1 = 1.f / den;
    float gg2 = __expf(b2v - b1v) / den;
    float dn = gg1 + gg2 + 1e-9f;
    e1[n] = i1; e2[n] = i2; g1[n] = gg1 / dn; g2[n] = gg2 / dn;
  }
}

// ---------------- capacity positions, single wave ----------------
__global__ __launch_bounds__(64) void k_positions(const int* __restrict__ e1, const int* __restrict__ e2,
                                                  const float* __restrict__ g1, const float* __restrict__ g2,
                                                  int* __restrict__ d1, int* __restrict__ d2,
                                                  float* __restrict__ s1, float* __restrict__ s2,
                                                  int* __restrict__ p2t) {
  const int lane = threadIdx.x;
  int base1[8] = {0, 0, 0, 0, 0, 0, 0, 0};
  int base2[8] = {0, 0, 0, 0, 0, 0, 0, 0};
  const unsigned long long lt = (1ull << lane) - 1ull;
  int na = e1[lane], nb = e2[lane];
  for (int c = 0; c < 64; c++) {
    int a = na, b = nb;
    if (c < 63) { na = e1[(c + 1) * 64 + lane]; nb = e2[(c + 1) * 64 + lane]; }
    int n = c * 64 + lane;
    int pa = 0, pb = 0;
    #pragma unroll
    for (int e = 0; e < 8; e++) {
      unsigned long long ba = __ballot(a == e);
      unsigned long long bb = __ballot(b == e);
      if (a == e) pa = base1[e] + __popcll(ba & lt);
      if (b == e) pb = base2[e] + __popcll(bb & lt);
      base1[e] += __popcll(ba);
      base2[e] += __popcll(bb);
    }
    d1[n] = a * CAP_ + (pa < CAP_ ? pa : CAP_ - 1);
    s1[n] = (pa < CAP_) ? g1[n] : 0.f;
    p2t[n] = pb;
  }
  __shared__ int c1[8];
  if (lane == 0) {
    c1[0] = base1[0]; c1[1] = base1[1]; c1[2] = base1[2]; c1[3] = base1[3];
    c1[4] = base1[4]; c1[5] = base1[5]; c1[6] = base1[6]; c1[7] = base1[7];
  }
  __syncthreads();
  for (int c = 0; c < 64; c++) {
    int n = c * 64 + lane;
    int b = e2[n];
    int pb = p2t[n] + c1[b];
    d2[n] = b * CAP_ + (pb < CAP_ ? pb : CAP_ - 1);
    s2[n] = (pb < CAP_) ? g2[n] : 0.f;
  }
}

// ---------------- scatter tokens into expert buffers ----------------
__global__ __launch_bounds__(256) void k_scatter(const float* __restrict__ x, const int* __restrict__ d1,
                                                 const int* __restrict__ d2, const float* __restrict__ s1,
                                                 const float* __restrict__ s2, bf16* __restrict__ buf) {
  int n = blockIdx.x;
  int tid = threadIdx.x;
  const float* xr = x + (long)n * 1024;
  float v[4];
  #pragma unroll
  for (int i = 0; i < 4; i++) v[i] = xr[tid + i * 256];
  if (s1[n] != 0.f) {
    bf16* o = buf + (long)d1[n] * 1024;
    #pragma unroll
    for (int i = 0; i < 4; i++) o[tid + i * 256] = (bf16)v[i];
  }
  if (s2[n] != 0.f) {
    bf16* o = buf + (long)d2[n] * 1024;
    #pragma unroll
    for (int i = 0; i < 4; i++) o[tid + i * 256] = (bf16)v[i];
  }
}

// ---------------- gather expert outputs + residual + final LN ----------------
__global__ __launch_bounds__(256) void k_gather_ln(const float* __restrict__ x, const float* __restrict__ eo,
                                                   const int* __restrict__ d1, const int* __restrict__ d2,
                                                   const float* __restrict__ s1, const float* __restrict__ s2,
                                                   const float* __restrict__ g, const float* __restrict__ be,
                                                   float* __restrict__ out) {
  long n = blockIdx.x;
  int tid = threadIdx.x;
  float a1 = s1[n], a2 = s2[n];
  const float* r1p = eo + (long)d1[n] * 1024;
  const float* r2p = eo + (long)d2[n] * 1024;
  const float* xr = x + n * 1024;
  float v[4];
  float s = 0.f, sq = 0.f;
  #pragma unroll
  for (int i = 0; i < 4; i++) {
    int c = tid + i * 256;
    float y = xr[c] + a1 * r1p[c] + a2 * r2p[c];
    v[i] = y; s += y; sq += y * y;
  }
  #pragma unroll
  for (int o = 32; o; o >>= 1) { s += __shfl_xor(s, o); sq += __shfl_xor(sq, o); }
  __shared__ float r1[4], r2[4];
  int wid = tid >> 6;
  if ((tid & 63) == 0) { r1[wid] = s; r2[wid] = sq; }
  __syncthreads();
  s = r1[0] + r1[1] + r1[2] + r1[3];
  sq = r2[0] + r2[1] + r2[2] + r2[3];
  float mu = s * (1.f / 1024.f);
  float var = sq * (1.f / 1024.f) - mu * mu;
  float rstd = rsqrtf(var + 1e-5f);
  #pragma unroll
  for (int i = 0; i < 4; i++) {
    int c = tid + i * 256;
    out[n * 1024 + c] = (v[i] - mu) * rstd * g[c] + be[c];
  }
}

// ---------------------------------------------------------------------------
extern "C" void kernel_launch(void* const* d_in, const int* in_sizes, int n_in,
                              void* d_out, int out_size, void* d_ws, size_t ws_size,
                              hipStream_t stream) {
  const float* tgt      = (const float*)d_in[0];
  const float* memory   = (const float*)d_in[1];
  const float* sa_in_w  = (const float*)d_in[2];
  const float* sa_in_b  = (const float*)d_in[3];
  const float* sa_out_w = (const float*)d_in[4];
  const float* sa_out_b = (const float*)d_in[5];
  const float* ca_in_w  = (const float*)d_in[6];
  const float* ca_in_b  = (const float*)d_in[7];
  const float* ca_out_w = (const float*)d_in[8];
  const float* ca_out_b = (const float*)d_in[9];
  const float* ln1_g    = (const float*)d_in[10];
  const float* ln1_b    = (const float*)d_in[11];
  const float* ln2_g    = (const float*)d_in[12];
  const float* ln2_b    = (const float*)d_in[13];
  const float* ln3_g    = (const float*)d_in[14];
  const float* ln3_b    = (const float*)d_in[15];
  const float* wg       = (const float*)d_in[16];
  const float* w1       = (const float*)d_in[17];
  const float* b1       = (const float*)d_in[18];
  const float* w2       = (const float*)d_in[19];
  const float* b2       = (const float*)d_in[20];

  char* ws = (char*)d_ws;
  auto B16 = [&](long o) { return (bf16*)(ws + o); };
  auto F32 = [&](long o) { return (float*)(ws + o); };
  auto I32 = [&](long o) { return (int*)(ws + o); };

  const dim3 blk256(256), blkT(64, 4);

  // ---- phase 0: conversions to bf16
  k_f32_to_bf16<<<3072, blk256, 0, stream>>>(sa_in_w, B16(OFF_WSAIN), 3072L * 1024 / 4);
  k_f32_to_bf16<<<1024, blk256, 0, stream>>>(sa_out_w, B16(OFF_WSAOUT), 1024L * 1024 / 4);
  k_f32_to_bf16<<<3072, blk256, 0, stream>>>(ca_in_w, B16(OFF_WCAIN), 3072L * 1024 / 4);
  k_f32_to_bf16<<<1024, blk256, 0, stream>>>(ca_out_w, B16(OFF_WCAOUT), 1024L * 1024 / 4);
  k_f32_to_bf16<<<4096, blk256, 0, stream>>>(tgt, B16(OFF_BTGT), 4096L * 1024 / 4);
  k_f32_to_bf16<<<4096, blk256, 0, stream>>>(memory, B16(OFF_BMEM), 4096L * 1024 / 4);

  // ---- phase 1: self-attention
  k_gemm_nt<128, 128, 2, 2, false, bf16><<<dim3(24, 32, 1), blk256, 0, stream>>>(
      B16(OFF_BTGT), B16(OFF_WSAIN), B16(OFF_QKV), sa_in_b,
      1024, 1024, 1024, 3072, 1.f, 1, 0, 0, 0, 0, 0, 0, 0, 0);
  k_extract_vt<<<dim3(1, 16, 64), blkT, 0, stream>>>(B16(OFF_QKV) + 2048, B16(OFF_VT), 12288, 3072);
  k_gemm_nt<128, 128, 2, 2, false, bf16><<<dim3(8, 8, 64), blk256, 0, stream>>>(
      B16(OFF_QKV), B16(OFF_QKV) + 1024, B16(OFF_SCORES), nullptr,
      64, 12288, 12288, 1024, 0.125f, 16,
      3072, 64, 3072, 64, 16L * TS_, TS_, 0, 0);
  k_softmax_row<<<65536, blk256, 0, stream>>>(B16(OFF_SCORES));
  k_gemm_nt<128, 64, 4, 1, false, bf16><<<dim3(1, 8, 64), blk256, 0, stream>>>(
      B16(OFF_SCORES), B16(OFF_VT), B16(OFF_AO), nullptr,
      1024, 1024, 1024, 4096, 1.f, 16,
      16L * TS_, TS_, 16L * 65536, 65536, 1024, 64, 0, 0);
  k_gemm_nt<128, 128, 2, 2, false, float><<<dim3(8, 32, 1), blk256, 0, stream>>>(
      B16(OFF_AO), B16(OFF_WSAOUT), F32(OFF_PROJ), sa_out_b,
      1024, 1024, 1024, 1024, 1.f, 1, 0, 0, 0, 0, 0, 0, 0, 0);
  k_add_ln<<<4096, blk256, 0, stream>>>(tgt, F32(OFF_PROJ), ln1_g, ln1_b, F32(OFF_X1), B16(OFF_BTGT));

  // ---- phase 2: cross-attention
  k_gemm_nt<128, 128, 2, 2, false, bf16><<<dim3(8, 32, 1), blk256, 0, stream>>>(
      B16(OFF_BTGT), B16(OFF_WCAIN), B16(OFF_QKV), ca_in_b,
      1024, 1024, 1024, 1024, 1.f, 1, 0, 0, 0, 0, 0, 0, 0, 0);
  k_gemm_nt<128, 128, 2, 2, false, bf16><<<dim3(16, 32, 1), blk256, 0, stream>>>(
      B16(OFF_BMEM), B16(OFF_WCAIN) + 1024L * 1024, B16(OFF_KVCA), ca_in_b + 1024,
      1024, 1024, 1024, 2048, 1.f, 1, 0, 0, 0, 0, 0, 0, 0, 0);
  k_extract_vt<<<dim3(1, 16, 64), blkT, 0, stream>>>(B16(OFF_KVCA) + 1024, B16(OFF_VT), 8192, 2048);
  k_gemm_nt<128, 128, 2, 2, false, bf16><<<dim3(8, 8, 64), blk256, 0, stream>>>(
      B16(OFF_QKV), B16(OFF_KVCA), B16(OFF_SCORES), nullptr,
      64, 4096, 8192, 1024, 0.125f, 16,
      1024, 64, 2048, 64, 16L * TS_, TS_, 0, 0);
  k_softmax_row<<<65536, blk256, 0, stream>>>(B16(OFF_SCORES));
  k_gemm_nt<128, 64, 4, 1, false, bf16><<<dim3(1, 8, 64), blk256, 0, stream>>>(
      B16(OFF_SCORES), B16(OFF_VT), B16(OFF_AO), nullptr,
      1024, 1024, 1024, 4096, 1.f, 16,
      16L * TS_, TS_, 16L * 65536, 65536, 1024, 64, 0, 0);
  k_gemm_nt<128, 128, 2, 2, false, float><<<dim3(8, 32, 1), blk256, 0, stream>>>(
      B16(OFF_AO), B16(OFF_WCAOUT), F32(OFF_PROJ), ca_out_b,
      1024, 1024, 1024, 1024, 1.f, 1, 0, 0, 0, 0, 0, 0, 0, 0);
  k_add_ln<<<4096, blk256, 0, stream>>>(F32(OFF_X1), F32(OFF_PROJ), ln2_g, ln2_b, F32(OFF_X2), (bf16*)nullptr);

  // ---- phase 3: MoE
  k_gate<<<1024, blk256, 0, stream>>>(F32(OFF_X2), wg, I32(OFF_E1), I32(OFF_E2), F32(OFF_G1), F32(OFF_G2));
  k_positions<<<1, 64, 0, stream>>>(I32(OFF_E1), I32(OFF_E2), F32(OFF_G1), F32(OFF_G2),
                                    I32(OFF_D1), I32(OFF_D2), F32(OFF_S1), F32(OFF_S2), I32(OFF_P2T));
  k_zero16<<<4096, blk256, 0, stream>>>((float4*)B16(OFF_QKV), 1048576L);
  k_scatter<<<4096, blk256, 0, stream>>>(F32(OFF_X2), I32(OFF_D1), I32(OFF_D2),
                                         F32(OFF_S1), F32(OFF_S2), B16(OFF_QKV));
  k_transpose_f32_bf16<<<dim3(64, 16, 8), blkT, 0, stream>>>(w1, B16(OFF_SCORES), 1024, 4096);
  k_gemm_nt<128, 128, 2, 2, true, bf16><<<dim3(32, 8, 8), blk256, 0, stream>>>(
      B16(OFF_QKV), B16(OFF_SCORES), B16(OFF_H), b1,
      1024, 1024, 1024, 4096, 1.f, 1,
      1048576, 0, 4194304, 0, 4194304, 0, 4096, 0);
  k_transpose_f32_bf16<<<dim3(16, 64, 8), blkT, 0, stream>>>(w2, B16(OFF_SCORES), 4096, 1024);
  k_gemm_nt<128, 128, 2, 2, false, float><<<dim3(8, 8, 8), blk256, 0, stream>>>(
      B16(OFF_H), B16(OFF_SCORES), F32(OFF_PROJ), b2,
      4096, 4096, 4096, 1024, 1.f, 1,
      4194304, 0, 4194304, 0, 1048576, 0, 1024, 0);
  k_gather_ln<<<4096, blk256, 0, stream>>>(F32(OFF_X2), F32(OFF_PROJ), I32(OFF_D1), I32(OFF_D2),
                                           F32(OFF_S1), F32(OFF_S2), ln3_g, ln3_b, (float*)d_out);

  (void)in_sizes; (void)n_in; (void)out_size; (void)ws_size;
}

// Round 3
// 748.769 us; speedup vs baseline: 1.4762x; 1.2094x over previous
//
#include <hip/hip_runtime.h>
#include <hip/hip_bf16.h>

// ---------------------------------------------------------------------------
// TransformerMoEDecoderLayer: SA -> add+LN -> CA -> add+LN -> MoE top2 -> add+LN
// T=S=1024, B=4, D=1024, H=16, HD=64, F=4096, E=8, N=4096, CAP=1024
// Round 3: fused flash attention (no scores materialization) + T1 XCD swizzle.
// ---------------------------------------------------------------------------

typedef __bf16 bf16;
typedef __bf16 bf16x4 __attribute__((ext_vector_type(4)));
typedef __bf16 bf16x8 __attribute__((ext_vector_type(8)));
typedef float  f32x4  __attribute__((ext_vector_type(4)));

static_assert(sizeof(bf16) == 2, "bf16 size");

#define CAP_ 1024

// global -> LDS direct copy, 16B per lane; LDS dest = base + lane*16 (linear)
#define GLOAD16(g, l)                                                  \
  __builtin_amdgcn_global_load_lds(                                    \
      (const __attribute__((address_space(1))) unsigned int*)(g),      \
      (__attribute__((address_space(3))) unsigned int*)(l), 16, 0, 0)

// ---------------- workspace layout (bytes) ----------------
static const long OFF_WSAIN  = 0L;                         // bf16 [3072][1024]
static const long OFF_WSAOUT = 6291456L;                   // bf16 [1024][1024]
static const long OFF_WCAIN  = 8388608L;                   // bf16 [3072][1024]
static const long OFF_WCAOUT = 14680064L;                  // bf16 [1024][1024]
static const long OFF_BTGT   = 16777216L;                  // bf16 [4096][1024]
static const long OFF_BMEM   = 25165824L;                  // bf16 [4096][1024]
static const long OFF_QKV    = 33554432L;                  // bf16 [4096][3072] (phase3: expert buf)
static const long OFF_KVCA   = OFF_QKV + 8388608L;         // bf16 [4096][2048]
static const long OFF_VT     = 58720256L;                  // bf16 [64][64][1024]
static const long OFF_AO     = 67108864L;                  // bf16 [4096][1024]
static const long OFF_PROJ   = 75497472L;                  // f32  [4096][1024] (phase3: eo f32 [8][1024][1024])
static const long OFF_X1     = 92274688L;                  // f32  [4096][1024]
static const long OFF_X2     = 109051904L;                 // f32  [4096][1024]
static const long OFF_SCORES = 125829120L;                 // phase3 only: w1t 64MB + h 64MB
static const long OFF_H      = OFF_SCORES + 67108864L;
static const long OFF_GATE   = 260046848L;
static const long OFF_E1   = OFF_GATE;
static const long OFF_E2   = OFF_GATE + 16384L;
static const long OFF_G1   = OFF_GATE + 32768L;
static const long OFF_G2   = OFF_GATE + 49152L;
static const long OFF_D1   = OFF_GATE + 65536L;
static const long OFF_D2   = OFF_GATE + 81920L;
static const long OFF_S1   = OFF_GATE + 98304L;
static const long OFF_S2   = OFF_GATE + 114688L;
static const long OFF_P2T  = OFF_GATE + 131072L;

// T1: bijective XCD chunk swizzle (m204). bid -> lid; consecutive lid share XCD.
__device__ __forceinline__ int xcd_swz(int bid, int nwg) {
  int q = nwg >> 3, r = nwg & 7;
  int xcd = bid & 7, idx = bid >> 3;
  return (xcd < r ? xcd * (q + 1) : r * (q + 1) + (xcd - r) * q) + idx;
}

// ---------------- elementwise fp32 -> bf16 ----------------
__global__ __launch_bounds__(256) void k_f32_to_bf16(const float* __restrict__ in,
                                                     bf16* __restrict__ out, long n4) {
  long i = (long)blockIdx.x * 256 + threadIdx.x;
  if (i >= n4) return;
  float4 v = ((const float4*)in)[i];
  bf16x4 o = {(bf16)v.x, (bf16)v.y, (bf16)v.z, (bf16)v.w};
  ((bf16x4*)out)[i] = o;
}

// ---------------- zero fill (16B granules) ----------------
__global__ __launch_bounds__(256) void k_zero16(float4* __restrict__ p, long n) {
  long i = (long)blockIdx.x * 256 + threadIdx.x;
  if (i < n) p[i] = make_float4(0.f, 0.f, 0.f, 0.f);
}

// ---------------- transpose fp32 [z][R][C] -> bf16 [z][C][R] ----------------
__global__ __launch_bounds__(256) void k_transpose_f32_bf16(const float* __restrict__ in,
                                                            bf16* __restrict__ out, int R, int C) {
  __shared__ float t[64][66];
  int z = blockIdx.z;
  long r0 = (long)blockIdx.y * 64, c0 = (long)blockIdx.x * 64;
  const float* ib = in + (long)z * R * C;
  bf16* ob = out + (long)z * R * C;
  int x = threadIdx.x, y = threadIdx.y;
  #pragma unroll
  for (int i = y; i < 64; i += 4) t[i][x] = ib[(r0 + i) * C + c0 + x];
  __syncthreads();
  #pragma unroll
  for (int i = y; i < 64; i += 4) ob[(c0 + i) * R + r0 + x] = (bf16)t[x][i];
}

// ---------------- extract V^T per head ----------------
__global__ __launch_bounds__(256) void k_extract_vt(const bf16* __restrict__ in,
                                                    bf16* __restrict__ out, long rs, long sb) {
  __shared__ bf16 t[64][66];
  int z = blockIdx.z;
  long r0 = (long)blockIdx.y * 64;
  const bf16* ib = in + (long)(z >> 4) * sb + (long)(z & 15) * 64;
  bf16* ob = out + (long)z * 64 * 1024;
  int x = threadIdx.x, y = threadIdx.y;
  #pragma unroll
  for (int i = y; i < 64; i += 4) t[i][x] = ib[(r0 + i) * rs + x];
  __syncthreads();
  #pragma unroll
  for (int i = y; i < 64; i += 4) ob[(long)i * 1024 + r0 + x] = t[x][i];
}

// ---------------- generic NT GEMM (m97 structure + T1 swizzle) ----------------
template <int BM, int BN, int WM, int WN, bool RELU, typename OutT>
__global__ __launch_bounds__(256) void k_gemm_nt(
    const bf16* __restrict__ A, const bf16* __restrict__ Bp,
    OutT* __restrict__ C, const float* __restrict__ bias,
    int K, long lda, long ldb, long ldc, float alpha, int zdiv,
    long sA1, long sA0, long sB1, long sB0, long sC1, long sC0,
    long sBias1, long sBias0) {
  constexpr int BK = 32;
  constexpr int WTM = BM / WM, WTN = BN / WN, MR = WTM / 16, NR = WTN / 16;
  constexpr int AISS = BM * BK / 2048;
  constexpr int BISS = BN * BK / 2048;
  __shared__ bf16 sa[BM * BK];
  __shared__ bf16 sb[BN * BK];
  // T1 swizzle
  const int nwg = gridDim.x * gridDim.y * gridDim.z;
  const int bid = blockIdx.x + gridDim.x * (blockIdx.y + gridDim.y * blockIdx.z);
  const int lid = xcd_swz(bid, nwg);
  const int bx = lid % gridDim.x;
  const int rem = lid / gridDim.x;
  const int by = rem % gridDim.y;
  const int z = rem / gridDim.y;
  const int zh = z / zdiv, zl = z - zh * zdiv;
  const bf16* Ab = A + zh * sA1 + zl * sA0 + (long)by * BM * lda;
  const bf16* Bb = Bp + zh * sB1 + zl * sB0 + (long)bx * BN * ldb;
  const int tid = threadIdx.x, lane = tid & 63, wid = tid >> 6;
  const int wm = wid / WN, wn = wid % WN;

  const int srow = tid >> 2;
  const int scol = (tid & 3) * 8;
  const bf16* aptr[AISS];
  bf16* aldst[AISS];
  #pragma unroll
  for (int i = 0; i < AISS; i++) {
    aptr[i] = Ab + (long)(srow + i * 64) * lda + scol;
    aldst[i] = &sa[i * 2048 + (wid << 9)];
  }
  const bf16* bptr[BISS];
  bf16* bldst[BISS];
  #pragma unroll
  for (int i = 0; i < BISS; i++) {
    bptr[i] = Bb + (long)(srow + i * 64) * ldb + scol;
    bldst[i] = &sb[i * 2048 + (wid << 9)];
  }

  f32x4 acc[MR][NR] = {};
  const int rA = wm * WTM + (lane & 15);
  const int rB = wn * WTN + (lane & 15);
  const int kk = (lane >> 4) * 8;

  for (int k0 = 0; k0 < K; k0 += BK) {
    #pragma unroll
    for (int i = 0; i < AISS; i++) GLOAD16(aptr[i] + k0, aldst[i]);
    #pragma unroll
    for (int i = 0; i < BISS; i++) GLOAD16(bptr[i] + k0, bldst[i]);
    __syncthreads();
    bf16x8 af[MR], bfr[NR];
    #pragma unroll
    for (int mi = 0; mi < MR; mi++) af[mi] = *(const bf16x8*)&sa[(rA + mi * 16) * BK + kk];
    #pragma unroll
    for (int ni = 0; ni < NR; ni++) bfr[ni] = *(const bf16x8*)&sb[(rB + ni * 16) * BK + kk];
    #pragma unroll
    for (int mi = 0; mi < MR; mi++)
      #pragma unroll
      for (int ni = 0; ni < NR; ni++)
        acc[mi][ni] = __builtin_amdgcn_mfma_f32_16x16x32_bf16(af[mi], bfr[ni], acc[mi][ni], 0, 0, 0);
    __syncthreads();
  }
  OutT* Cb = C + zh * sC1 + zl * sC0;
  const float* biasb = bias ? (bias + zh * sBias1 + zl * sBias0) : nullptr;
  const long rowBase = (long)by * BM + wm * WTM + ((lane >> 4) * 4);
  const long colBase = (long)bx * BN + wn * WTN + (lane & 15);
  #pragma unroll
  for (int mi = 0; mi < MR; mi++) {
    #pragma unroll
    for (int ni = 0; ni < NR; ni++) {
      long col = colBase + ni * 16;
      float bv = biasb ? biasb[col] : 0.f;
      #pragma unroll
      for (int r = 0; r < 4; r++) {
        long row = rowBase + mi * 16 + r;
        float v = acc[mi][ni][r] * alpha + bv;
        if (RELU) v = fmaxf(v, 0.f);
        Cb[row * ldc + col] = (OutT)v;
      }
    }
  }
}

// ---------------- fused flash attention ----------------
// One block = one (b,h) x one 128-row Q tile. 4 waves, each owns 32 Q rows.
// Q,K accessed by token stride (qrs/krs elems); b-section offset = rs/4*b.
// V^T from vt[bh][64][1024]. Online softmax; O accum f32; out -> ao[n][h*64+d].
__global__ __launch_bounds__(256) void k_flash(
    const bf16* __restrict__ q, const bf16* __restrict__ kk,
    const bf16* __restrict__ vt, bf16* __restrict__ ao,
    long qrs, long krs) {
  __shared__ bf16 kt[2][2048];    // [d-half][64 s][32 d]
  __shared__ bf16 vtt[2][2048];   // [s-half][64 d][32 s]
  __shared__ bf16 p_lds[4][32 * 72];
  const int nwg = gridDim.x * gridDim.y;
  const int bid = blockIdx.x + gridDim.x * blockIdx.y;
  const int lid = xcd_swz(bid, nwg);
  const int qt = lid & 7;          // gridDim.x == 8 (Q tiles), fastest
  const int bh = lid >> 3;
  const int b = bh >> 4, h = bh & 15;
  const int tid = threadIdx.x, lane = tid & 63, wid = tid >> 6;
  const int colLane = lane & 15, grp = lane >> 4;
  const bf16* qb = q + (qrs >> 2) * b + h * 64;
  const bf16* kb = kk + (krs >> 2) * b + h * 64;
  const bf16* vb = vt + (long)bh * 65536;

  // Q fragments (once per block): rows qt*128 + wid*32 + mi*16 + colLane
  bf16x8 qf[2][2];
  const int qrow0 = qt * 128 + wid * 32 + colLane;
  #pragma unroll
  for (int mi = 0; mi < 2; mi++)
    #pragma unroll
    for (int ks = 0; ks < 2; ks++)
      qf[mi][ks] = *(const bf16x8*)&qb[(long)(qrow0 + mi * 16) * qrs + ks * 32 + grp * 8];

  const int srow = tid >> 2;           // 0..63
  const int scol = (tid & 3) * 8;      // 0,8,16,24

  f32x4 oacc[2][4] = {};
  float m_[2][4], l_[2][4];
  #pragma unroll
  for (int mi = 0; mi < 2; mi++)
    #pragma unroll
    for (int r = 0; r < 4; r++) { m_[mi][r] = -INFINITY; l_[mi][r] = 0.f; }
  bf16* pl = &p_lds[wid][0];

  for (int s0 = 0; s0 < 1024; s0 += 64) {
    // stage K tile (2 d-halves) and V^T tile (2 s-halves)
    GLOAD16(&kb[(long)(s0 + srow) * krs + scol], &kt[0][wid << 9]);
    GLOAD16(&kb[(long)(s0 + srow) * krs + 32 + scol], &kt[1][wid << 9]);
    GLOAD16(&vb[(long)srow * 1024 + s0 + scol], &vtt[0][wid << 9]);
    GLOAD16(&vb[(long)srow * 1024 + s0 + 32 + scol], &vtt[1][wid << 9]);
    __syncthreads();

    // S = Q K^T
    f32x4 sacc[2][4] = {};
    bf16x8 kf[4][2];
    #pragma unroll
    for (int ni = 0; ni < 4; ni++)
      #pragma unroll
      for (int ks = 0; ks < 2; ks++)
        kf[ni][ks] = *(const bf16x8*)&kt[ks][(colLane + ni * 16) * 32 + grp * 8];
    #pragma unroll
    for (int ks = 0; ks < 2; ks++)
      #pragma unroll
      for (int mi = 0; mi < 2; mi++)
        #pragma unroll
        for (int ni = 0; ni < 4; ni++)
          sacc[mi][ni] = __builtin_amdgcn_mfma_f32_16x16x32_bf16(qf[mi][ks], kf[ni][ks], sacc[mi][ni], 0, 0, 0);

    // online softmax: row = mi*16 + grp*4 + r, col = ni*16 + colLane
    float mnew[2][4], sc[2][4], psum[2][4];
    #pragma unroll
    for (int mi = 0; mi < 2; mi++)
      #pragma unroll
      for (int r = 0; r < 4; r++) {
        float vx = fmaxf(fmaxf(sacc[mi][0][r], sacc[mi][1][r]),
                         fmaxf(sacc[mi][2][r], sacc[mi][3][r])) * 0.125f;
        #pragma unroll
        for (int o = 1; o < 16; o <<= 1) vx = fmaxf(vx, __shfl_xor(vx, o));
        float mn = fmaxf(m_[mi][r], vx);
        sc[mi][r] = __expf(m_[mi][r] - mn);
        m_[mi][r] = mn; mnew[mi][r] = mn;
        l_[mi][r] *= sc[mi][r];
        psum[mi][r] = 0.f;
      }
    #pragma unroll
    for (int mi = 0; mi < 2; mi++)
      #pragma unroll
      for (int ni = 0; ni < 4; ni++)
        #pragma unroll
        for (int r = 0; r < 4; r++)
          oacc[mi][ni][r] *= sc[mi][r];
    #pragma unroll
    for (int mi = 0; mi < 2; mi++)
      #pragma unroll
      for (int ni = 0; ni < 4; ni++)
        #pragma unroll
        for (int r = 0; r < 4; r++) {
          float p = __expf(sacc[mi][ni][r] * 0.125f - mnew[mi][r]);
          psum[mi][r] += p;
          pl[(mi * 16 + grp * 4 + r) * 72 + ni * 16 + colLane] = (bf16)p;
        }
    #pragma unroll
    for (int mi = 0; mi < 2; mi++)
      #pragma unroll
      for (int r = 0; r < 4; r++) {
        float ps = psum[mi][r];
        #pragma unroll
        for (int o = 1; o < 16; o <<= 1) ps += __shfl_xor(ps, o);
        l_[mi][r] += ps;
      }

    // O += P V  (P from per-wave LDS; V^T fragments)
    bf16x8 pa[2][2], vf[4][2];
    #pragma unroll
    for (int mi = 0; mi < 2; mi++)
      #pragma unroll
      for (int ks = 0; ks < 2; ks++)
        pa[mi][ks] = *(const bf16x8*)&pl[(colLane + mi * 16) * 72 + ks * 32 + grp * 8];
    #pragma unroll
    for (int ni = 0; ni < 4; ni++)
      #pragma unroll
      for (int ks = 0; ks < 2; ks++)
        vf[ni][ks] = *(const bf16x8*)&vtt[ks][(colLane + ni * 16) * 32 + grp * 8];
    #pragma unroll
    for (int ks = 0; ks < 2; ks++)
      #pragma unroll
      for (int mi = 0; mi < 2; mi++)
        #pragma unroll
        for (int ni = 0; ni < 4; ni++)
          oacc[mi][ni] = __builtin_amdgcn_mfma_f32_16x16x32_bf16(pa[mi][ks], vf[ni][ks], oacc[mi][ni], 0, 0, 0);
    __syncthreads();
  }

  // epilogue: divide by l, store to ao[t*4+b][h*64+d]
  #pragma unroll
  for (int mi = 0; mi < 2; mi++)
    #pragma unroll
    for (int r = 0; r < 4; r++) {
      float inv = 1.f / l_[mi][r];
      int t = qt * 128 + wid * 32 + mi * 16 + grp * 4 + r;
      long n = (long)t * 4 + b;
      #pragma unroll
      for (int ni = 0; ni < 4; ni++)
        ao[n * 1024 + h * 64 + ni * 16 + colLane] = (bf16)(oacc[mi][ni][r] * inv);
    }
}

// ---------------- residual add + LayerNorm ----------------
__global__ __launch_bounds__(256) void k_add_ln(const float* __restrict__ a, const float* __restrict__ b,
                                                const float* __restrict__ g, const float* __restrict__ be,
                                                float* __restrict__ out, bf16* __restrict__ outb) {
  long row = blockIdx.x;
  int tid = threadIdx.x;
  const float* pa = a + row * 1024;
  const float* pb = b + row * 1024;
  float v[4];
  float s = 0.f, sq = 0.f;
  #pragma unroll
  for (int i = 0; i < 4; i++) {
    int c = tid + i * 256;
    float x = pa[c] + pb[c];
    v[i] = x; s += x; sq += x * x;
  }
  #pragma unroll
  for (int o = 32; o; o >>= 1) { s += __shfl_xor(s, o); sq += __shfl_xor(sq, o); }
  __shared__ float r1[4], r2[4];
  int wid = tid >> 6;
  if ((tid & 63) == 0) { r1[wid] = s; r2[wid] = sq; }
  __syncthreads();
  s = r1[0] + r1[1] + r1[2] + r1[3];
  sq = r2[0] + r2[1] + r2[2] + r2[3];
  float mu = s * (1.f / 1024.f);
  float var = sq * (1.f / 1024.f) - mu * mu;
  float rstd = rsqrtf(var + 1e-5f);
  #pragma unroll
  for (int i = 0; i < 4; i++) {
    int c = tid + i * 256;
    float y = (v[i] - mu) * rstd * g[c] + be[c];
    out[row * 1024 + c] = y;
    if (outb) outb[row * 1024 + c] = (bf16)y;
  }
}

// ---------------- MoE gating ----------------
__global__ __launch_bounds__(256) void k_gate(const float* __restrict__ x, const float* __restrict__ wg,
                                              int* __restrict__ e1, int* __restrict__ e2,
                                              float* __restrict__ g1, float* __restrict__ g2) {
  int n = blockIdx.x * 4 + (threadIdx.x >> 6);
  int lane = threadIdx.x & 63;
  const float* xr = x + (long)n * 1024;
  float acc[8] = {0.f, 0.f, 0.f, 0.f, 0.f, 0.f, 0.f, 0.f};
  for (int i = 0; i < 16; i++) {
    float xv = xr[i * 64 + lane];
    const float* wr = wg + (long)(i * 64 + lane) * 8;
    #pragma unroll
    for (int e = 0; e < 8; e++) acc[e] += xv * wr[e];
  }
  #pragma unroll
  for (int e = 0; e < 8; e++)
    #pragma unroll
    for (int o = 32; o; o >>= 1) acc[e] += __shfl_xor(acc[e], o);
  if (lane == 0) {
    int i1 = 0; float b1v = acc[0];
    #pragma unroll
    for (int e = 1; e < 8; e++) if (acc[e] > b1v) { b1v = acc[e]; i1 = e; }
    int i2 = -1; float b2v = -INFINITY;
    #pragma unroll
    for (int e = 0; e < 8; e++) if (e != i1 && acc[e] > b2v) { b2v = acc[e]; i2 = e; }
    float den = 0.f;
    #pragma unroll
    for (int e = 0; e < 8; e++) den += __expf(acc[e] - b1v);
    float gg1 = 1.f / den;
    float gg2 = __expf(b2v - b1v) / den;
    float dn = gg1 + gg2 + 1e-9f;
    e1[n] = i1; e2[n] = i2; g1[n] = gg1 / dn; g2[n] = gg2 / dn;
  }
}

// ---------------- capacity positions, single wave ----------------
__global__ __launch_bounds__(64) void k_positions(const int* __restrict__ e1, const int* __restrict__ e2,
                                                  const float* __restrict__ g1, const float* __restrict__ g2,
                                                  int* __restrict__ d1, int* __restrict__ d2,
                                                  float* __restrict__ s1, float* __restrict__ s2,
                                                  int* __restrict__ p2t) {
  const int lane = threadIdx.x;
  int base1[8] = {0, 0, 0, 0, 0, 0, 0, 0};
  int base2[8] = {0, 0, 0, 0, 0, 0, 0, 0};
  const unsigned long long lt = (1ull << lane) - 1ull;
  int na = e1[lane], nb = e2[lane];
  for (int c = 0; c < 64; c++) {
    int a = na, b = nb;
    if (c < 63) { na = e1[(c + 1) * 64 + lane]; nb = e2[(c + 1) * 64 + lane]; }
    int n = c * 64 + lane;
    int pa = 0, pb = 0;
    #pragma unroll
    for (int e = 0; e < 8; e++) {
      unsigned long long ba = __ballot(a == e);
      unsigned long long bb = __ballot(b == e);
      if (a == e) pa = base1[e] + __popcll(ba & lt);
      if (b == e) pb = base2[e] + __popcll(bb & lt);
      base1[e] += __popcll(ba);
      base2[e] += __popcll(bb);
    }
    d1[n] = a * CAP_ + (pa < CAP_ ? pa : CAP_ - 1);
    s1[n] = (pa < CAP_) ? g1[n] : 0.f;
    p2t[n] = pb;
  }
  __shared__ int c1[8];
  if (lane == 0) {
    c1[0] = base1[0]; c1[1] = base1[1]; c1[2] = base1[2]; c1[3] = base1[3];
    c1[4] = base1[4]; c1[5] = base1[5]; c1[6] = base1[6]; c1[7] = base1[7];
  }
  __syncthreads();
  for (int c = 0; c < 64; c++) {
    int n = c * 64 + lane;
    int b = e2[n];
    int pb = p2t[n] + c1[b];
    d2[n] = b * CAP_ + (pb < CAP_ ? pb : CAP_ - 1);
    s2[n] = (pb < CAP_) ? g2[n] : 0.f;
  }
}

// ---------------- scatter tokens into expert buffers ----------------
__global__ __launch_bounds__(256) void k_scatter(const float* __restrict__ x, const int* __restrict__ d1,
                                                 const int* __restrict__ d2, const float* __restrict__ s1,
                                                 const float* __restrict__ s2, bf16* __restrict__ buf) {
  int n = blockIdx.x;
  int tid = threadIdx.x;
  const float* xr = x + (long)n * 1024;
  float v[4];
  #pragma unroll
  for (int i = 0; i < 4; i++) v[i] = xr[tid + i * 256];
  if (s1[n] != 0.f) {
    bf16* o = buf + (long)d1[n] * 1024;
    #pragma unroll
    for (int i = 0; i < 4; i++) o[tid + i * 256] = (bf16)v[i];
  }
  if (s2[n] != 0.f) {
    bf16* o = buf + (long)d2[n] * 1024;
    #pragma unroll
    for (int i = 0; i < 4; i++) o[tid + i * 256] = (bf16)v[i];
  }
}

// ---------------- gather expert outputs + residual + final LN ----------------
__global__ __launch_bounds__(256) void k_gather_ln(const float* __restrict__ x, const float* __restrict__ eo,
                                                   const int* __restrict__ d1, const int* __restrict__ d2,
                                                   const float* __restrict__ s1, const float* __restrict__ s2,
                                                   const float* __restrict__ g, const float* __restrict__ be,
                                                   float* __restrict__ out) {
  long n = blockIdx.x;
  int tid = threadIdx.x;
  float a1 = s1[n], a2 = s2[n];
  const float* r1p = eo + (long)d1[n] * 1024;
  const float* r2p = eo + (long)d2[n] * 1024;
  const float* xr = x + n * 1024;
  float v[4];
  float s = 0.f, sq = 0.f;
  #pragma unroll
  for (int i = 0; i < 4; i++) {
    int c = tid + i * 256;
    float y = xr[c] + a1 * r1p[c] + a2 * r2p[c];
    v[i] = y; s += y; sq += y * y;
  }
  #pragma unroll
  for (int o = 32; o; o >>= 1) { s += __shfl_xor(s, o); sq += __shfl_xor(sq, o); }
  __shared__ float r1[4], r2[4];
  int wid = tid >> 6;
  if ((tid & 63) == 0) { r1[wid] = s; r2[wid] = sq; }
  __syncthreads();
  s = r1[0] + r1[1] + r1[2] + r1[3];
  sq = r2[0] + r2[1] + r2[2] + r2[3];
  float mu = s * (1.f / 1024.f);
  float var = sq * (1.f / 1024.f) - mu * mu;
  float rstd = rsqrtf(var + 1e-5f);
  #pragma unroll
  for (int i = 0; i < 4; i++) {
    int c = tid + i * 256;
    out[n * 1024 + c] = (v[i] - mu) * rstd * g[c] + be[c];
  }
}

// ---------------------------------------------------------------------------
extern "C" void kernel_launch(void* const* d_in, const int* in_sizes, int n_in,
                              void* d_out, int out_size, void* d_ws, size_t ws_size,
                              hipStream_t stream) {
  const float* tgt      = (const float*)d_in[0];
  const float* memory   = (const float*)d_in[1];
  const float* sa_in_w  = (const float*)d_in[2];
  const float* sa_in_b  = (const float*)d_in[3];
  const float* sa_out_w = (const float*)d_in[4];
  const float* sa_out_b = (const float*)d_in[5];
  const float* ca_in_w  = (const float*)d_in[6];
  const float* ca_in_b  = (const float*)d_in[7];
  const float* ca_out_w = (const float*)d_in[8];
  const float* ca_out_b = (const float*)d_in[9];
  const float* ln1_g    = (const float*)d_in[10];
  const float* ln1_b    = (const float*)d_in[11];
  const float* ln2_g    = (const float*)d_in[12];
  const float* ln2_b    = (const float*)d_in[13];
  const float* ln3_g    = (const float*)d_in[14];
  const float* ln3_b    = (const float*)d_in[15];
  const float* wg       = (const float*)d_in[16];
  const float* w1       = (const float*)d_in[17];
  const float* b1       = (const float*)d_in[18];
  const float* w2       = (const float*)d_in[19];
  const float* b2       = (const float*)d_in[20];

  char* ws = (char*)d_ws;
  auto B16 = [&](long o) { return (bf16*)(ws + o); };
  auto F32 = [&](long o) { return (float*)(ws + o); };
  auto I32 = [&](long o) { return (int*)(ws + o); };

  const dim3 blk256(256), blkT(64, 4);

  // ---- phase 0: conversions to bf16
  k_f32_to_bf16<<<3072, blk256, 0, stream>>>(sa_in_w, B16(OFF_WSAIN), 3072L * 1024 / 4);
  k_f32_to_bf16<<<1024, blk256, 0, stream>>>(sa_out_w, B16(OFF_WSAOUT), 1024L * 1024 / 4);
  k_f32_to_bf16<<<3072, blk256, 0, stream>>>(ca_in_w, B16(OFF_WCAIN), 3072L * 1024 / 4);
  k_f32_to_bf16<<<1024, blk256, 0, stream>>>(ca_out_w, B16(OFF_WCAOUT), 1024L * 1024 / 4);
  k_f32_to_bf16<<<4096, blk256, 0, stream>>>(tgt, B16(OFF_BTGT), 4096L * 1024 / 4);
  k_f32_to_bf16<<<4096, blk256, 0, stream>>>(memory, B16(OFF_BMEM), 4096L * 1024 / 4);

  // ---- phase 1: self-attention
  k_gemm_nt<128, 128, 2, 2, false, bf16><<<dim3(24, 32, 1), blk256, 0, stream>>>(
      B16(OFF_BTGT), B16(OFF_WSAIN), B16(OFF_QKV), sa_in_b,
      1024, 1024, 1024, 3072, 1.f, 1, 0, 0, 0, 0, 0, 0, 0, 0);
  k_extract_vt<<<dim3(1, 16, 64), blkT, 0, stream>>>(B16(OFF_QKV) + 2048, B16(OFF_VT), 12288, 3072);
  k_flash<<<dim3(8, 64), blk256, 0, stream>>>(
      B16(OFF_QKV), B16(OFF_QKV) + 1024, B16(OFF_VT), B16(OFF_AO), 12288, 12288);
  k_gemm_nt<128, 128, 2, 2, false, float><<<dim3(8, 32, 1), blk256, 0, stream>>>(
      B16(OFF_AO), B16(OFF_WSAOUT), F32(OFF_PROJ), sa_out_b,
      1024, 1024, 1024, 1024, 1.f, 1, 0, 0, 0, 0, 0, 0, 0, 0);
  k_add_ln<<<4096, blk256, 0, stream>>>(tgt, F32(OFF_PROJ), ln1_g, ln1_b, F32(OFF_X1), B16(OFF_BTGT));

  // ---- phase 2: cross-attention
  k_gemm_nt<128, 128, 2, 2, false, bf16><<<dim3(8, 32, 1), blk256, 0, stream>>>(
      B16(OFF_BTGT), B16(OFF_WCAIN), B16(OFF_QKV), ca_in_b,
      1024, 1024, 1024, 1024, 1.f, 1, 0, 0, 0, 0, 0, 0, 0, 0);
  k_gemm_nt<128, 128, 2, 2, false, bf16><<<dim3(16, 32, 1), blk256, 0, stream>>>(
      B16(OFF_BMEM), B16(OFF_WCAIN) + 1024L * 1024, B16(OFF_KVCA), ca_in_b + 1024,
      1024, 1024, 1024, 2048, 1.f, 1, 0, 0, 0, 0, 0, 0, 0, 0);
  k_extract_vt<<<dim3(1, 16, 64), blkT, 0, stream>>>(B16(OFF_KVCA) + 1024, B16(OFF_VT), 8192, 2048);
  k_flash<<<dim3(8, 64), blk256, 0, stream>>>(
      B16(OFF_QKV), B16(OFF_KVCA), B16(OFF_VT), B16(OFF_AO), 4096, 8192);
  k_gemm_nt<128, 128, 2, 2, false, float><<<dim3(8, 32, 1), blk256, 0, stream>>>(
      B16(OFF_AO), B16(OFF_WCAOUT), F32(OFF_PROJ), ca_out_b,
      1024, 1024, 1024, 1024, 1.f, 1, 0, 0, 0, 0, 0, 0, 0, 0);
  k_add_ln<<<4096, blk256, 0, stream>>>(F32(OFF_X1), F32(OFF_PROJ), ln2_g, ln2_b, F32(OFF_X2), (bf16*)nullptr);

  // ---- phase 3: MoE
  k_gate<<<1024, blk256, 0, stream>>>(F32(OFF_X2), wg, I32(OFF_E1), I32(OFF_E2), F32(OFF_G1), F32(OFF_G2));
  k_positions<<<1, 64, 0, stream>>>(I32(OFF_E1), I32(OFF_E2), F32(OFF_G1), F32(OFF_G2),
                                    I32(OFF_D1), I32(OFF_D2), F32(OFF_S1), F32(OFF_S2), I32(OFF_P2T));
  k_zero16<<<4096, blk256, 0, stream>>>((float4*)B16(OFF_QKV), 1048576L);
  k_scatter<<<4096, blk256, 0, stream>>>(F32(OFF_X2), I32(OFF_D1), I32(OFF_D2),
                                         F32(OFF_S1), F32(OFF_S2), B16(OFF_QKV));
  k_transpose_f32_bf16<<<dim3(64, 16, 8), blkT, 0, stream>>>(w1, B16(OFF_SCORES), 1024, 4096);
  k_gemm_nt<128, 128, 2, 2, true, bf16><<<dim3(32, 8, 8), blk256, 0, stream>>>(
      B16(OFF_QKV), B16(OFF_SCORES), B16(OFF_H), b1,
      1024, 1024, 1024, 4096, 1.f, 1,
      1048576, 0, 4194304, 0, 4194304, 0, 4096, 0);
  k_transpose_f32_bf16<<<dim3(16, 64, 8), blkT, 0, stream>>>(w2, B16(OFF_SCORES), 4096, 1024);
  k_gemm_nt<128, 128, 2, 2, false, float><<<dim3(8, 8, 8), blk256, 0, stream>>>(
      B16(OFF_H), B16(OFF_SCORES), F32(OFF_PROJ), b2,
      4096, 4096, 4096, 1024, 1.f, 1,
      4194304, 0, 4194304, 0, 1048576, 0, 1024, 0);
  k_gather_ln<<<4096, blk256, 0, stream>>>(F32(OFF_X2), F32(OFF_PROJ), I32(OFF_D1), I32(OFF_D2),
                                           F32(OFF_S1), F32(OFF_S2), ln3_g, ln3_b, (float*)d_out);

  (void)in_sizes; (void)n_in; (void)out_size; (void)ws_size;
}

// Round 4
// 727.187 us; speedup vs baseline: 1.5200x; 1.0297x over previous
//
#include <hip/hip_runtime.h>
#include <hip/hip_bf16.h>

// ---------------------------------------------------------------------------
// TransformerMoEDecoderLayer: SA -> add+LN -> CA -> add+LN -> MoE top2 -> add+LN
// T=S=1024, B=4, D=1024, H=16, HD=64, F=4096, E=8, N=4096, CAP=1024
// Round 4: split-K eo GEMM (occupancy), 128x64 tiles for N<=2048 GEMMs,
//          vectorized weight transposes.
// ---------------------------------------------------------------------------

typedef __bf16 bf16;
typedef __bf16 bf16x2 __attribute__((ext_vector_type(2)));
typedef __bf16 bf16x4 __attribute__((ext_vector_type(4)));
typedef __bf16 bf16x8 __attribute__((ext_vector_type(8)));
typedef float  f32x4  __attribute__((ext_vector_type(4)));

static_assert(sizeof(bf16) == 2, "bf16 size");

#define CAP_ 1024

// global -> LDS direct copy, 16B per lane; LDS dest = base + lane*16 (linear)
#define GLOAD16(g, l)                                                  \
  __builtin_amdgcn_global_load_lds(                                    \
      (const __attribute__((address_space(1))) unsigned int*)(g),      \
      (__attribute__((address_space(3))) unsigned int*)(l), 16, 0, 0)

// ---------------- workspace layout (bytes) ----------------
static const long OFF_WSAIN  = 0L;                         // bf16 [3072][1024]
static const long OFF_WSAOUT = 6291456L;                   // bf16 [1024][1024]
static const long OFF_WCAIN  = 8388608L;                   // bf16 [3072][1024]
static const long OFF_WCAOUT = 14680064L;                  // bf16 [1024][1024]
static const long OFF_BTGT   = 16777216L;                  // bf16 [4096][1024]
static const long OFF_BMEM   = 25165824L;                  // bf16 [4096][1024]
static const long OFF_QKV    = 33554432L;                  // bf16 [4096][3072] (phase3: expert buf; then eo partial1 32MB)
static const long OFF_EO1    = 33554432L;                  // f32 [8192][1024] partial1 (phase3, after h GEMM)
static const long OFF_KVCA   = OFF_QKV + 8388608L;         // bf16 [4096][2048]
static const long OFF_VT     = 58720256L;                  // bf16 [64][64][1024]
static const long OFF_AO     = 67108864L;                  // bf16 [4096][1024]
static const long OFF_PROJ   = 75497472L;                  // f32  [4096][1024] (phase3: eo partial0 spans PROJ+X1)
static const long OFF_X1     = 92274688L;                  // f32  [4096][1024]
static const long OFF_X2     = 109051904L;                 // f32  [4096][1024]
static const long OFF_SCORES = 125829120L;                 // phase3: w1t/w2t 64MB + h 64MB
static const long OFF_H      = OFF_SCORES + 67108864L;
static const long OFF_GATE   = 260046848L;
static const long OFF_E1   = OFF_GATE;
static const long OFF_E2   = OFF_GATE + 16384L;
static const long OFF_G1   = OFF_GATE + 32768L;
static const long OFF_G2   = OFF_GATE + 49152L;
static const long OFF_D1   = OFF_GATE + 65536L;
static const long OFF_D2   = OFF_GATE + 81920L;
static const long OFF_S1   = OFF_GATE + 98304L;
static const long OFF_S2   = OFF_GATE + 114688L;
static const long OFF_P2T  = OFF_GATE + 131072L;

// T1: bijective XCD chunk swizzle (m204). bid -> lid; consecutive lid share XCD.
__device__ __forceinline__ int xcd_swz(int bid, int nwg) {
  int q = nwg >> 3, r = nwg & 7;
  int xcd = bid & 7, idx = bid >> 3;
  return (xcd < r ? xcd * (q + 1) : r * (q + 1) + (xcd - r) * q) + idx;
}

// ---------------- elementwise fp32 -> bf16 ----------------
__global__ __launch_bounds__(256) void k_f32_to_bf16(const float* __restrict__ in,
                                                     bf16* __restrict__ out, long n4) {
  long i = (long)blockIdx.x * 256 + threadIdx.x;
  if (i >= n4) return;
  float4 v = ((const float4*)in)[i];
  bf16x4 o = {(bf16)v.x, (bf16)v.y, (bf16)v.z, (bf16)v.w};
  ((bf16x4*)out)[i] = o;
}

// ---------------- zero fill (16B granules) ----------------
__global__ __launch_bounds__(256) void k_zero16(float4* __restrict__ p, long n) {
  long i = (long)blockIdx.x * 256 + threadIdx.x;
  if (i < n) p[i] = make_float4(0.f, 0.f, 0.f, 0.f);
}

// ---------------- transpose fp32 [z][R][C] -> bf16 [z][C][R], vectorized ----
// block (16,16); 64x64 tile; float4 loads; bf16x2 packed stores.
__global__ __launch_bounds__(256) void k_transpose_f32_bf16(const float* __restrict__ in,
                                                            bf16* __restrict__ out, int R, int C) {
  __shared__ float t[64][70];
  int z = blockIdx.z;
  long r0 = (long)blockIdx.y * 64, c0 = (long)blockIdx.x * 64;
  const float* ib = in + (long)z * R * C;
  bf16* ob = out + (long)z * R * C;
  int x = threadIdx.x, y = threadIdx.y;   // 16 x 16
  #pragma unroll
  for (int j = 0; j < 4; j++) {
    int sr = y + j * 16;
    float4 v = *(const float4*)&ib[(r0 + sr) * C + c0 + x * 4];
    t[sr][x * 4 + 0] = v.x; t[sr][x * 4 + 1] = v.y;
    t[sr][x * 4 + 2] = v.z; t[sr][x * 4 + 3] = v.w;
  }
  __syncthreads();
  #pragma unroll
  for (int j = 0; j < 4; j++) {
    int sc = y + j * 16;
    #pragma unroll
    for (int i = 0; i < 2; i++) {
      int sr = x * 2 + i * 32;
      bf16x2 o = {(bf16)t[sr][sc], (bf16)t[sr + 1][sc]};
      *(bf16x2*)&ob[(c0 + sc) * R + r0 + sr] = o;
    }
  }
}

// ---------------- extract V^T per head ----------------
__global__ __launch_bounds__(256) void k_extract_vt(const bf16* __restrict__ in,
                                                    bf16* __restrict__ out, long rs, long sb) {
  __shared__ bf16 t[64][66];
  int z = blockIdx.z;
  long r0 = (long)blockIdx.y * 64;
  const bf16* ib = in + (long)(z >> 4) * sb + (long)(z & 15) * 64;
  bf16* ob = out + (long)z * 64 * 1024;
  int x = threadIdx.x, y = threadIdx.y;
  #pragma unroll
  for (int i = y; i < 64; i += 4) t[i][x] = ib[(r0 + i) * rs + x];
  __syncthreads();
  #pragma unroll
  for (int i = y; i < 64; i += 4) ob[(long)i * 1024 + r0 + x] = t[x][i];
}

// ---------------- generic NT GEMM (m97 structure + T1 swizzle) ----------------
template <int BM, int BN, int WM, int WN, bool RELU, typename OutT>
__global__ __launch_bounds__(256) void k_gemm_nt(
    const bf16* __restrict__ A, const bf16* __restrict__ Bp,
    OutT* __restrict__ C, const float* __restrict__ bias,
    int K, long lda, long ldb, long ldc, float alpha, int zdiv,
    long sA1, long sA0, long sB1, long sB0, long sC1, long sC0,
    long sBias1, long sBias0) {
  constexpr int BK = 32;
  constexpr int WTM = BM / WM, WTN = BN / WN, MR = WTM / 16, NR = WTN / 16;
  constexpr int AISS = BM * BK / 2048;
  constexpr int BISS = BN * BK / 2048;
  __shared__ bf16 sa[BM * BK];
  __shared__ bf16 sb[BN * BK];
  // T1 swizzle
  const int nwg = gridDim.x * gridDim.y * gridDim.z;
  const int bid = blockIdx.x + gridDim.x * (blockIdx.y + gridDim.y * blockIdx.z);
  const int lid = xcd_swz(bid, nwg);
  const int bx = lid % gridDim.x;
  const int rem = lid / gridDim.x;
  const int by = rem % gridDim.y;
  const int z = rem / gridDim.y;
  const int zh = z / zdiv, zl = z - zh * zdiv;
  const bf16* Ab = A + zh * sA1 + zl * sA0 + (long)by * BM * lda;
  const bf16* Bb = Bp + zh * sB1 + zl * sB0 + (long)bx * BN * ldb;
  const int tid = threadIdx.x, lane = tid & 63, wid = tid >> 6;
  const int wm = wid / WN, wn = wid % WN;

  const int srow = tid >> 2;
  const int scol = (tid & 3) * 8;
  const bf16* aptr[AISS];
  bf16* aldst[AISS];
  #pragma unroll
  for (int i = 0; i < AISS; i++) {
    aptr[i] = Ab + (long)(srow + i * 64) * lda + scol;
    aldst[i] = &sa[i * 2048 + (wid << 9)];
  }
  const bf16* bptr[BISS];
  bf16* bldst[BISS];
  #pragma unroll
  for (int i = 0; i < BISS; i++) {
    bptr[i] = Bb + (long)(srow + i * 64) * ldb + scol;
    bldst[i] = &sb[i * 2048 + (wid << 9)];
  }

  f32x4 acc[MR][NR] = {};
  const int rA = wm * WTM + (lane & 15);
  const int rB = wn * WTN + (lane & 15);
  const int kk = (lane >> 4) * 8;

  for (int k0 = 0; k0 < K; k0 += BK) {
    #pragma unroll
    for (int i = 0; i < AISS; i++) GLOAD16(aptr[i] + k0, aldst[i]);
    #pragma unroll
    for (int i = 0; i < BISS; i++) GLOAD16(bptr[i] + k0, bldst[i]);
    __syncthreads();
    bf16x8 af[MR], bfr[NR];
    #pragma unroll
    for (int mi = 0; mi < MR; mi++) af[mi] = *(const bf16x8*)&sa[(rA + mi * 16) * BK + kk];
    #pragma unroll
    for (int ni = 0; ni < NR; ni++) bfr[ni] = *(const bf16x8*)&sb[(rB + ni * 16) * BK + kk];
    #pragma unroll
    for (int mi = 0; mi < MR; mi++)
      #pragma unroll
      for (int ni = 0; ni < NR; ni++)
        acc[mi][ni] = __builtin_amdgcn_mfma_f32_16x16x32_bf16(af[mi], bfr[ni], acc[mi][ni], 0, 0, 0);
    __syncthreads();
  }
  OutT* Cb = C + zh * sC1 + zl * sC0;
  const float* biasb = bias ? (bias + zh * sBias1 + zl * sBias0) : nullptr;
  const long rowBase = (long)by * BM + wm * WTM + ((lane >> 4) * 4);
  const long colBase = (long)bx * BN + wn * WTN + (lane & 15);
  #pragma unroll
  for (int mi = 0; mi < MR; mi++) {
    #pragma unroll
    for (int ni = 0; ni < NR; ni++) {
      long col = colBase + ni * 16;
      float bv = biasb ? biasb[col] : 0.f;
      #pragma unroll
      for (int r = 0; r < 4; r++) {
        long row = rowBase + mi * 16 + r;
        float v = acc[mi][ni][r] * alpha + bv;
        if (RELU) v = fmaxf(v, 0.f);
        Cb[row * ldc + col] = (OutT)v;
      }
    }
  }
}

// ---------------- fused flash attention ----------------
__global__ __launch_bounds__(256) void k_flash(
    const bf16* __restrict__ q, const bf16* __restrict__ kk,
    const bf16* __restrict__ vt, bf16* __restrict__ ao,
    long qrs, long krs) {
  __shared__ bf16 kt[2][2048];
  __shared__ bf16 vtt[2][2048];
  __shared__ bf16 p_lds[4][32 * 72];
  const int nwg = gridDim.x * gridDim.y;
  const int bid = blockIdx.x + gridDim.x * blockIdx.y;
  const int lid = xcd_swz(bid, nwg);
  const int qt = lid & 7;
  const int bh = lid >> 3;
  const int b = bh >> 4, h = bh & 15;
  const int tid = threadIdx.x, lane = tid & 63, wid = tid >> 6;
  const int colLane = lane & 15, grp = lane >> 4;
  const bf16* qb = q + (qrs >> 2) * b + h * 64;
  const bf16* kb = kk + (krs >> 2) * b + h * 64;
  const bf16* vb = vt + (long)bh * 65536;

  bf16x8 qf[2][2];
  const int qrow0 = qt * 128 + wid * 32 + colLane;
  #pragma unroll
  for (int mi = 0; mi < 2; mi++)
    #pragma unroll
    for (int ks = 0; ks < 2; ks++)
      qf[mi][ks] = *(const bf16x8*)&qb[(long)(qrow0 + mi * 16) * qrs + ks * 32 + grp * 8];

  const int srow = tid >> 2;
  const int scol = (tid & 3) * 8;

  f32x4 oacc[2][4] = {};
  float m_[2][4], l_[2][4];
  #pragma unroll
  for (int mi = 0; mi < 2; mi++)
    #pragma unroll
    for (int r = 0; r < 4; r++) { m_[mi][r] = -INFINITY; l_[mi][r] = 0.f; }
  bf16* pl = &p_lds[wid][0];

  for (int s0 = 0; s0 < 1024; s0 += 64) {
    GLOAD16(&kb[(long)(s0 + srow) * krs + scol], &kt[0][wid << 9]);
    GLOAD16(&kb[(long)(s0 + srow) * krs + 32 + scol], &kt[1][wid << 9]);
    GLOAD16(&vb[(long)srow * 1024 + s0 + scol], &vtt[0][wid << 9]);
    GLOAD16(&vb[(long)srow * 1024 + s0 + 32 + scol], &vtt[1][wid << 9]);
    __syncthreads();

    f32x4 sacc[2][4] = {};
    bf16x8 kf[4][2];
    #pragma unroll
    for (int ni = 0; ni < 4; ni++)
      #pragma unroll
      for (int ks = 0; ks < 2; ks++)
        kf[ni][ks] = *(const bf16x8*)&kt[ks][(colLane + ni * 16) * 32 + grp * 8];
    #pragma unroll
    for (int ks = 0; ks < 2; ks++)
      #pragma unroll
      for (int mi = 0; mi < 2; mi++)
        #pragma unroll
        for (int ni = 0; ni < 4; ni++)
          sacc[mi][ni] = __builtin_amdgcn_mfma_f32_16x16x32_bf16(qf[mi][ks], kf[ni][ks], sacc[mi][ni], 0, 0, 0);

    float mnew[2][4], sc[2][4], psum[2][4];
    #pragma unroll
    for (int mi = 0; mi < 2; mi++)
      #pragma unroll
      for (int r = 0; r < 4; r++) {
        float vx = fmaxf(fmaxf(sacc[mi][0][r], sacc[mi][1][r]),
                         fmaxf(sacc[mi][2][r], sacc[mi][3][r])) * 0.125f;
        #pragma unroll
        for (int o = 1; o < 16; o <<= 1) vx = fmaxf(vx, __shfl_xor(vx, o));
        float mn = fmaxf(m_[mi][r], vx);
        sc[mi][r] = __expf(m_[mi][r] - mn);
        m_[mi][r] = mn; mnew[mi][r] = mn;
        l_[mi][r] *= sc[mi][r];
        psum[mi][r] = 0.f;
      }
    #pragma unroll
    for (int mi = 0; mi < 2; mi++)
      #pragma unroll
      for (int ni = 0; ni < 4; ni++)
        #pragma unroll
        for (int r = 0; r < 4; r++)
          oacc[mi][ni][r] *= sc[mi][r];
    #pragma unroll
    for (int mi = 0; mi < 2; mi++)
      #pragma unroll
      for (int ni = 0; ni < 4; ni++)
        #pragma unroll
        for (int r = 0; r < 4; r++) {
          float p = __expf(sacc[mi][ni][r] * 0.125f - mnew[mi][r]);
          psum[mi][r] += p;
          pl[(mi * 16 + grp * 4 + r) * 72 + ni * 16 + colLane] = (bf16)p;
        }
    #pragma unroll
    for (int mi = 0; mi < 2; mi++)
      #pragma unroll
      for (int r = 0; r < 4; r++) {
        float ps = psum[mi][r];
        #pragma unroll
        for (int o = 1; o < 16; o <<= 1) ps += __shfl_xor(ps, o);
        l_[mi][r] += ps;
      }

    bf16x8 pa[2][2], vf[4][2];
    #pragma unroll
    for (int mi = 0; mi < 2; mi++)
      #pragma unroll
      for (int ks = 0; ks < 2; ks++)
        pa[mi][ks] = *(const bf16x8*)&pl[(colLane + mi * 16) * 72 + ks * 32 + grp * 8];
    #pragma unroll
    for (int ni = 0; ni < 4; ni++)
      #pragma unroll
      for (int ks = 0; ks < 2; ks++)
        vf[ni][ks] = *(const bf16x8*)&vtt[ks][(colLane + ni * 16) * 32 + grp * 8];
    #pragma unroll
    for (int ks = 0; ks < 2; ks++)
      #pragma unroll
      for (int mi = 0; mi < 2; mi++)
        #pragma unroll
        for (int ni = 0; ni < 4; ni++)
          oacc[mi][ni] = __builtin_amdgcn_mfma_f32_16x16x32_bf16(pa[mi][ks], vf[ni][ks], oacc[mi][ni], 0, 0, 0);
    __syncthreads();
  }

  #pragma unroll
  for (int mi = 0; mi < 2; mi++)
    #pragma unroll
    for (int r = 0; r < 4; r++) {
      float inv = 1.f / l_[mi][r];
      int t = qt * 128 + wid * 32 + mi * 16 + grp * 4 + r;
      long n = (long)t * 4 + b;
      #pragma unroll
      for (int ni = 0; ni < 4; ni++)
        ao[n * 1024 + h * 64 + ni * 16 + colLane] = (bf16)(oacc[mi][ni][r] * inv);
    }
}

// ---------------- residual add + LayerNorm ----------------
__global__ __launch_bounds__(256) void k_add_ln(const float* __restrict__ a, const float* __restrict__ b,
                                                const float* __restrict__ g, const float* __restrict__ be,
                                                float* __restrict__ out, bf16* __restrict__ outb) {
  long row = blockIdx.x;
  int tid = threadIdx.x;
  const float* pa = a + row * 1024;
  const float* pb = b + row * 1024;
  float v[4];
  float s = 0.f, sq = 0.f;
  #pragma unroll
  for (int i = 0; i < 4; i++) {
    int c = tid + i * 256;
    float x = pa[c] + pb[c];
    v[i] = x; s += x; sq += x * x;
  }
  #pragma unroll
  for (int o = 32; o; o >>= 1) { s += __shfl_xor(s, o); sq += __shfl_xor(sq, o); }
  __shared__ float r1[4], r2[4];
  int wid = tid >> 6;
  if ((tid & 63) == 0) { r1[wid] = s; r2[wid] = sq; }
  __syncthreads();
  s = r1[0] + r1[1] + r1[2] + r1[3];
  sq = r2[0] + r2[1] + r2[2] + r2[3];
  float mu = s * (1.f / 1024.f);
  float var = sq * (1.f / 1024.f) - mu * mu;
  float rstd = rsqrtf(var + 1e-5f);
  #pragma unroll
  for (int i = 0; i < 4; i++) {
    int c = tid + i * 256;
    float y = (v[i] - mu) * rstd * g[c] + be[c];
    out[row * 1024 + c] = y;
    if (outb) outb[row * 1024 + c] = (bf16)y;
  }
}

// ---------------- MoE gating ----------------
__global__ __launch_bounds__(256) void k_gate(const float* __restrict__ x, const float* __restrict__ wg,
                                              int* __restrict__ e1, int* __restrict__ e2,
                                              float* __restrict__ g1, float* __restrict__ g2) {
  int n = blockIdx.x * 4 + (threadIdx.x >> 6);
  int lane = threadIdx.x & 63;
  const float* xr = x + (long)n * 1024;
  float acc[8] = {0.f, 0.f, 0.f, 0.f, 0.f, 0.f, 0.f, 0.f};
  for (int i = 0; i < 16; i++) {
    float xv = xr[i * 64 + lane];
    const float* wr = wg + (long)(i * 64 + lane) * 8;
    #pragma unroll
    for (int e = 0; e < 8; e++) acc[e] += xv * wr[e];
  }
  #pragma unroll
  for (int e = 0; e < 8; e++)
    #pragma unroll
    for (int o = 32; o; o >>= 1) acc[e] += __shfl_xor(acc[e], o);
  if (lane == 0) {
    int i1 = 0; float b1v = acc[0];
    #pragma unroll
    for (int e = 1; e < 8; e++) if (acc[e] > b1v) { b1v = acc[e]; i1 = e; }
    int i2 = -1; float b2v = -INFINITY;
    #pragma unroll
    for (int e = 0; e < 8; e++) if (e != i1 && acc[e] > b2v) { b2v = acc[e]; i2 = e; }
    float den = 0.f;
    #pragma unroll
    for (int e = 0; e < 8; e++) den += __expf(acc[e] - b1v);
    float gg1 = 1.f / den;
    float gg2 = __expf(b2v - b1v) / den;
    float dn = gg1 + gg2 + 1e-9f;
    e1[n] = i1; e2[n] = i2; g1[n] = gg1 / dn; g2[n] = gg2 / dn;
  }
}

// ---------------- capacity positions, single wave ----------------
__global__ __launch_bounds__(64) void k_positions(const int* __restrict__ e1, const int* __restrict__ e2,
                                                  const float* __restrict__ g1, const float* __restrict__ g2,
                                                  int* __restrict__ d1, int* __restrict__ d2,
                                                  float* __restrict__ s1, float* __restrict__ s2,
                                                  int* __restrict__ p2t) {
  const int lane = threadIdx.x;
  int base1[8] = {0, 0, 0, 0, 0, 0, 0, 0};
  int base2[8] = {0, 0, 0, 0, 0, 0, 0, 0};
  const unsigned long long lt = (1ull << lane) - 1ull;
  int na = e1[lane], nb = e2[lane];
  for (int c = 0; c < 64; c++) {
    int a = na, b = nb;
    if (c < 63) { na = e1[(c + 1) * 64 + lane]; nb = e2[(c + 1) * 64 + lane]; }
    int n = c * 64 + lane;
    int pa = 0, pb = 0;
    #pragma unroll
    for (int e = 0; e < 8; e++) {
      unsigned long long ba = __ballot(a == e);
      unsigned long long bb = __ballot(b == e);
      if (a == e) pa = base1[e] + __popcll(ba & lt);
      if (b == e) pb = base2[e] + __popcll(bb & lt);
      base1[e] += __popcll(ba);
      base2[e] += __popcll(bb);
    }
    d1[n] = a * CAP_ + (pa < CAP_ ? pa : CAP_ - 1);
    s1[n] = (pa < CAP_) ? g1[n] : 0.f;
    p2t[n] = pb;
  }
  __shared__ int c1[8];
  if (lane == 0) {
    c1[0] = base1[0]; c1[1] = base1[1]; c1[2] = base1[2]; c1[3] = base1[3];
    c1[4] = base1[4]; c1[5] = base1[5]; c1[6] = base1[6]; c1[7] = base1[7];
  }
  __syncthreads();
  for (int c = 0; c < 64; c++) {
    int n = c * 64 + lane;
    int b = e2[n];
    int pb = p2t[n] + c1[b];
    d2[n] = b * CAP_ + (pb < CAP_ ? pb : CAP_ - 1);
    s2[n] = (pb < CAP_) ? g2[n] : 0.f;
  }
}

// ---------------- scatter tokens into expert buffers ----------------
__global__ __launch_bounds__(256) void k_scatter(const float* __restrict__ x, const int* __restrict__ d1,
                                                 const int* __restrict__ d2, const float* __restrict__ s1,
                                                 const float* __restrict__ s2, bf16* __restrict__ buf) {
  int n = blockIdx.x;
  int tid = threadIdx.x;
  const float* xr = x + (long)n * 1024;
  float v[4];
  #pragma unroll
  for (int i = 0; i < 4; i++) v[i] = xr[tid + i * 256];
  if (s1[n] != 0.f) {
    bf16* o = buf + (long)d1[n] * 1024;
    #pragma unroll
    for (int i = 0; i < 4; i++) o[tid + i * 256] = (bf16)v[i];
  }
  if (s2[n] != 0.f) {
    bf16* o = buf + (long)d2[n] * 1024;
    #pragma unroll
    for (int i = 0; i < 4; i++) o[tid + i * 256] = (bf16)v[i];
  }
}

// ---------------- gather expert outputs (2 split-K partials + b2) + LN3 ------
__global__ __launch_bounds__(256) void k_gather_ln(const float* __restrict__ x,
                                                   const float* __restrict__ p0, const float* __restrict__ p1,
                                                   const float* __restrict__ b2,
                                                   const int* __restrict__ d1, const int* __restrict__ d2,
                                                   const float* __restrict__ s1, const float* __restrict__ s2,
                                                   const float* __restrict__ g, const float* __restrict__ be,
                                                   float* __restrict__ out) {
  long n = blockIdx.x;
  int tid = threadIdx.x;
  float a1 = s1[n], a2 = s2[n];
  long i1 = (long)d1[n] * 1024, i2 = (long)d2[n] * 1024;
  long e1b = (long)(d1[n] >> 10) * 1024, e2b = (long)(d2[n] >> 10) * 1024;
  const float* xr = x + n * 1024;
  float v[4];
  float s = 0.f, sq = 0.f;
  #pragma unroll
  for (int i = 0; i < 4; i++) {
    int c = tid + i * 256;
    float r1v = p0[i1 + c] + p1[i1 + c] + b2[e1b + c];
    float r2v = p0[i2 + c] + p1[i2 + c] + b2[e2b + c];
    float y = xr[c] + a1 * r1v + a2 * r2v;
    v[i] = y; s += y; sq += y * y;
  }
  #pragma unroll
  for (int o = 32; o; o >>= 1) { s += __shfl_xor(s, o); sq += __shfl_xor(sq, o); }
  __shared__ float r1[4], r2[4];
  int wid = tid >> 6;
  if ((tid & 63) == 0) { r1[wid] = s; r2[wid] = sq; }
  __syncthreads();
  s = r1[0] + r1[1] + r1[2] + r1[3];
  sq = r2[0] + r2[1] + r2[2] + r2[3];
  float mu = s * (1.f / 1024.f);
  float var = sq * (1.f / 1024.f) - mu * mu;
  float rstd = rsqrtf(var + 1e-5f);
  #pragma unroll
  for (int i = 0; i < 4; i++) {
    int c = tid + i * 256;
    out[n * 1024 + c] = (v[i] - mu) * rstd * g[c] + be[c];
  }
}

// ---------------------------------------------------------------------------
extern "C" void kernel_launch(void* const* d_in, const int* in_sizes, int n_in,
                              void* d_out, int out_size, void* d_ws, size_t ws_size,
                              hipStream_t stream) {
  const float* tgt      = (const float*)d_in[0];
  const float* memory   = (const float*)d_in[1];
  const float* sa_in_w  = (const float*)d_in[2];
  const float* sa_in_b  = (const float*)d_in[3];
  const float* sa_out_w = (const float*)d_in[4];
  const float* sa_out_b = (const float*)d_in[5];
  const float* ca_in_w  = (const float*)d_in[6];
  const float* ca_in_b  = (const float*)d_in[7];
  const float* ca_out_w = (const float*)d_in[8];
  const float* ca_out_b = (const float*)d_in[9];
  const float* ln1_g    = (const float*)d_in[10];
  const float* ln1_b    = (const float*)d_in[11];
  const float* ln2_g    = (const float*)d_in[12];
  const float* ln2_b    = (const float*)d_in[13];
  const float* ln3_g    = (const float*)d_in[14];
  const float* ln3_b    = (const float*)d_in[15];
  const float* wg       = (const float*)d_in[16];
  const float* w1       = (const float*)d_in[17];
  const float* b1       = (const float*)d_in[18];
  const float* w2       = (const float*)d_in[19];
  const float* b2       = (const float*)d_in[20];

  char* ws = (char*)d_ws;
  auto B16 = [&](long o) { return (bf16*)(ws + o); };
  auto F32 = [&](long o) { return (float*)(ws + o); };
  auto I32 = [&](long o) { return (int*)(ws + o); };

  const dim3 blk256(256), blkT16(16, 16), blkT(64, 4);

  // ---- phase 0: conversions to bf16
  k_f32_to_bf16<<<3072, blk256, 0, stream>>>(sa_in_w, B16(OFF_WSAIN), 3072L * 1024 / 4);
  k_f32_to_bf16<<<1024, blk256, 0, stream>>>(sa_out_w, B16(OFF_WSAOUT), 1024L * 1024 / 4);
  k_f32_to_bf16<<<3072, blk256, 0, stream>>>(ca_in_w, B16(OFF_WCAIN), 3072L * 1024 / 4);
  k_f32_to_bf16<<<1024, blk256, 0, stream>>>(ca_out_w, B16(OFF_WCAOUT), 1024L * 1024 / 4);
  k_f32_to_bf16<<<4096, blk256, 0, stream>>>(tgt, B16(OFF_BTGT), 4096L * 1024 / 4);
  k_f32_to_bf16<<<4096, blk256, 0, stream>>>(memory, B16(OFF_BMEM), 4096L * 1024 / 4);

  // ---- phase 1: self-attention
  k_gemm_nt<128, 128, 2, 2, false, bf16><<<dim3(24, 32, 1), blk256, 0, stream>>>(
      B16(OFF_BTGT), B16(OFF_WSAIN), B16(OFF_QKV), sa_in_b,
      1024, 1024, 1024, 3072, 1.f, 1, 0, 0, 0, 0, 0, 0, 0, 0);
  k_extract_vt<<<dim3(1, 16, 64), blkT, 0, stream>>>(B16(OFF_QKV) + 2048, B16(OFF_VT), 12288, 3072);
  k_flash<<<dim3(8, 64), blk256, 0, stream>>>(
      B16(OFF_QKV), B16(OFF_QKV) + 1024, B16(OFF_VT), B16(OFF_AO), 12288, 12288);
  k_gemm_nt<128, 64, 4, 1, false, float><<<dim3(16, 32, 1), blk256, 0, stream>>>(
      B16(OFF_AO), B16(OFF_WSAOUT), F32(OFF_PROJ), sa_out_b,
      1024, 1024, 1024, 1024, 1.f, 1, 0, 0, 0, 0, 0, 0, 0, 0);
  k_add_ln<<<4096, blk256, 0, stream>>>(tgt, F32(OFF_PROJ), ln1_g, ln1_b, F32(OFF_X1), B16(OFF_BTGT));

  // ---- phase 2: cross-attention
  k_gemm_nt<128, 64, 4, 1, false, bf16><<<dim3(16, 32, 1), blk256, 0, stream>>>(
      B16(OFF_BTGT), B16(OFF_WCAIN), B16(OFF_QKV), ca_in_b,
      1024, 1024, 1024, 1024, 1.f, 1, 0, 0, 0, 0, 0, 0, 0, 0);
  k_gemm_nt<128, 64, 4, 1, false, bf16><<<dim3(32, 32, 1), blk256, 0, stream>>>(
      B16(OFF_BMEM), B16(OFF_WCAIN) + 1024L * 1024, B16(OFF_KVCA), ca_in_b + 1024,
      1024, 1024, 1024, 2048, 1.f, 1, 0, 0, 0, 0, 0, 0, 0, 0);
  k_extract_vt<<<dim3(1, 16, 64), blkT, 0, stream>>>(B16(OFF_KVCA) + 1024, B16(OFF_VT), 8192, 2048);
  k_flash<<<dim3(8, 64), blk256, 0, stream>>>(
      B16(OFF_QKV), B16(OFF_KVCA), B16(OFF_VT), B16(OFF_AO), 4096, 8192);
  k_gemm_nt<128, 64, 4, 1, false, float><<<dim3(16, 32, 1), blk256, 0, stream>>>(
      B16(OFF_AO), B16(OFF_WCAOUT), F32(OFF_PROJ), ca_out_b,
      1024, 1024, 1024, 1024, 1.f, 1, 0, 0, 0, 0, 0, 0, 0, 0);
  k_add_ln<<<4096, blk256, 0, stream>>>(F32(OFF_X1), F32(OFF_PROJ), ln2_g, ln2_b, F32(OFF_X2), (bf16*)nullptr);

  // ---- phase 3: MoE
  k_gate<<<1024, blk256, 0, stream>>>(F32(OFF_X2), wg, I32(OFF_E1), I32(OFF_E2), F32(OFF_G1), F32(OFF_G2));
  k_positions<<<1, 64, 0, stream>>>(I32(OFF_E1), I32(OFF_E2), F32(OFF_G1), F32(OFF_G2),
                                    I32(OFF_D1), I32(OFF_D2), F32(OFF_S1), F32(OFF_S2), I32(OFF_P2T));
  k_zero16<<<4096, blk256, 0, stream>>>((float4*)B16(OFF_QKV), 1048576L);
  k_scatter<<<4096, blk256, 0, stream>>>(F32(OFF_X2), I32(OFF_D1), I32(OFF_D2),
                                         F32(OFF_S1), F32(OFF_S2), B16(OFF_QKV));
  // w1t[e] = w1[e]^T : [4096][1024] bf16
  k_transpose_f32_bf16<<<dim3(64, 16, 8), blkT16, 0, stream>>>(w1, B16(OFF_SCORES), 1024, 4096);
  // h = relu(buf @ w1t^T + b1) : [8][1024][4096] bf16
  k_gemm_nt<128, 128, 2, 2, true, bf16><<<dim3(32, 8, 8), blk256, 0, stream>>>(
      B16(OFF_QKV), B16(OFF_SCORES), B16(OFF_H), b1,
      1024, 1024, 1024, 4096, 1.f, 1,
      1048576, 0, 4194304, 0, 4194304, 0, 4096, 0);
  // w2t[e] = w2[e]^T : [1024][4096] bf16 (overwrite w1t)
  k_transpose_f32_bf16<<<dim3(16, 64, 8), blkT16, 0, stream>>>(w2, B16(OFF_SCORES), 4096, 1024);
  // eo = h @ w2t^T (split-K=2, no bias) -> partial0 @PROJ, partial1 @EO1
  k_gemm_nt<128, 128, 2, 2, false, float><<<dim3(8, 8, 16), blk256, 0, stream>>>(
      B16(OFF_H), B16(OFF_SCORES), F32(OFF_PROJ), nullptr,
      2048, 4096, 4096, 1024, 1.f, 2,
      4194304, 2048, 4194304, 2048, 1048576, (OFF_EO1 - OFF_PROJ) / 4, 0, 0);
  // gather + b2 + residual + LN3 -> out
  k_gather_ln<<<4096, blk256, 0, stream>>>(F32(OFF_X2), F32(OFF_PROJ), F32(OFF_EO1), b2,
                                           I32(OFF_D1), I32(OFF_D2),
                                           F32(OFF_S1), F32(OFF_S2), ln3_g, ln3_b, (float*)d_out);

  (void)in_sizes; (void)n_in; (void)out_size; (void)ws_size;
}

// Round 5
// 636.186 us; speedup vs baseline: 1.7374x; 1.1430x over previous
//
#include <hip/hip_runtime.h>
#include <hip/hip_bf16.h>

// ---------------------------------------------------------------------------
// TransformerMoEDecoderLayer: SA -> add+LN -> CA -> add+LN -> MoE top2 -> add+LN
// T=S=1024, B=4, D=1024, H=16, HD=64, F=4096, E=8, N=4096, CAP=1024
// Round 5: 256^2 8-phase GEMM (T2+T3+T4+T5) for MoE h/eo GEMMs.
// ---------------------------------------------------------------------------

typedef __bf16 bf16;
typedef __bf16 bf16x2 __attribute__((ext_vector_type(2)));
typedef __bf16 bf16x4 __attribute__((ext_vector_type(4)));
typedef __bf16 bf16x8 __attribute__((ext_vector_type(8)));
typedef float  f32x4  __attribute__((ext_vector_type(4)));

static_assert(sizeof(bf16) == 2, "bf16 size");

#define CAP_ 1024

// global -> LDS direct copy, 16B per lane; LDS dest = wave-uniform base (+lane*16 by HW)
#define GLOAD16(g, l)                                                  \
  __builtin_amdgcn_global_load_lds(                                    \
      (const __attribute__((address_space(1))) unsigned int*)(g),      \
      (__attribute__((address_space(3))) unsigned int*)(l), 16, 0, 0)

#define BAR() do { asm volatile("" ::: "memory"); __builtin_amdgcn_s_barrier(); asm volatile("" ::: "memory"); } while (0)

// ---------------- workspace layout (bytes) ----------------
static const long OFF_WSAIN  = 0L;                         // bf16 [3072][1024]
static const long OFF_WSAOUT = 6291456L;                   // bf16 [1024][1024]
static const long OFF_WCAIN  = 8388608L;                   // bf16 [3072][1024]
static const long OFF_WCAOUT = 14680064L;                  // bf16 [1024][1024]
static const long OFF_BTGT   = 16777216L;                  // bf16 [4096][1024]
static const long OFF_BMEM   = 25165824L;                  // bf16 [4096][1024]
static const long OFF_QKV    = 33554432L;                  // bf16 [4096][3072] (phase3: expert buf; then eo partial1)
static const long OFF_EO1    = 33554432L;                  // f32 [8][1024][1024] partial1
static const long OFF_KVCA   = OFF_QKV + 8388608L;         // bf16 [4096][2048]
static const long OFF_VT     = 58720256L;                  // bf16 [64][64][1024]
static const long OFF_AO     = 67108864L;                  // bf16 [4096][1024]
static const long OFF_PROJ   = 75497472L;                  // f32  [4096][1024] (phase3: eo partial0)
static const long OFF_X1     = 92274688L;                  // f32  [4096][1024]
static const long OFF_X2     = 109051904L;                 // f32  [4096][1024]
static const long OFF_SCORES = 125829120L;                 // phase3: w1t/w2t 64MB
static const long OFF_H      = OFF_SCORES + 67108864L;     // bf16 [8][1024][4096]
static const long OFF_GATE   = 260046848L;
static const long OFF_E1   = OFF_GATE;
static const long OFF_E2   = OFF_GATE + 16384L;
static const long OFF_G1   = OFF_GATE + 32768L;
static const long OFF_G2   = OFF_GATE + 49152L;
static const long OFF_D1   = OFF_GATE + 65536L;
static const long OFF_D2   = OFF_GATE + 81920L;
static const long OFF_S1   = OFF_GATE + 98304L;
static const long OFF_S2   = OFF_GATE + 114688L;
static const long OFF_P2T  = OFF_GATE + 131072L;

// T1: bijective XCD chunk swizzle (m204).
__device__ __forceinline__ int xcd_swz(int bid, int nwg) {
  int q = nwg >> 3, r = nwg & 7;
  int xcd = bid & 7, idx = bid >> 3;
  return (xcd < r ? xcd * (q + 1) : r * (q + 1) + (xcd - r) * q) + idx;
}

// ---------------- elementwise fp32 -> bf16 ----------------
__global__ __launch_bounds__(256) void k_f32_to_bf16(const float* __restrict__ in,
                                                     bf16* __restrict__ out, long n4) {
  long i = (long)blockIdx.x * 256 + threadIdx.x;
  if (i >= n4) return;
  float4 v = ((const float4*)in)[i];
  bf16x4 o = {(bf16)v.x, (bf16)v.y, (bf16)v.z, (bf16)v.w};
  ((bf16x4*)out)[i] = o;
}

// ---------------- zero fill ----------------
__global__ __launch_bounds__(256) void k_zero16(float4* __restrict__ p, long n) {
  long i = (long)blockIdx.x * 256 + threadIdx.x;
  if (i < n) p[i] = make_float4(0.f, 0.f, 0.f, 0.f);
}

// ---------------- transpose fp32 [z][R][C] -> bf16 [z][C][R], vectorized ----
__global__ __launch_bounds__(256) void k_transpose_f32_bf16(const float* __restrict__ in,
                                                            bf16* __restrict__ out, int R, int C) {
  __shared__ float t[64][70];
  int z = blockIdx.z;
  long r0 = (long)blockIdx.y * 64, c0 = (long)blockIdx.x * 64;
  const float* ib = in + (long)z * R * C;
  bf16* ob = out + (long)z * R * C;
  int x = threadIdx.x, y = threadIdx.y;   // 16 x 16
  #pragma unroll
  for (int j = 0; j < 4; j++) {
    int sr = y + j * 16;
    float4 v = *(const float4*)&ib[(r0 + sr) * C + c0 + x * 4];
    t[sr][x * 4 + 0] = v.x; t[sr][x * 4 + 1] = v.y;
    t[sr][x * 4 + 2] = v.z; t[sr][x * 4 + 3] = v.w;
  }
  __syncthreads();
  #pragma unroll
  for (int j = 0; j < 4; j++) {
    int sc = y + j * 16;
    #pragma unroll
    for (int i = 0; i < 2; i++) {
      int sr = x * 2 + i * 32;
      bf16x2 o = {(bf16)t[sr][sc], (bf16)t[sr + 1][sc]};
      *(bf16x2*)&ob[(c0 + sc) * R + r0 + sr] = o;
    }
  }
}

// ---------------- extract V^T per head ----------------
__global__ __launch_bounds__(256) void k_extract_vt(const bf16* __restrict__ in,
                                                    bf16* __restrict__ out, long rs, long sb) {
  __shared__ bf16 t[64][66];
  int z = blockIdx.z;
  long r0 = (long)blockIdx.y * 64;
  const bf16* ib = in + (long)(z >> 4) * sb + (long)(z & 15) * 64;
  bf16* ob = out + (long)z * 64 * 1024;
  int x = threadIdx.x, y = threadIdx.y;
  #pragma unroll
  for (int i = y; i < 64; i += 4) t[i][x] = ib[(r0 + i) * rs + x];
  __syncthreads();
  #pragma unroll
  for (int i = y; i < 64; i += 4) ob[(long)i * 1024 + r0 + x] = t[x][i];
}

// ---------------- generic NT GEMM (m97 structure + T1 swizzle) ----------------
template <int BM, int BN, int WM, int WN, bool RELU, typename OutT>
__global__ __launch_bounds__(256) void k_gemm_nt(
    const bf16* __restrict__ A, const bf16* __restrict__ Bp,
    OutT* __restrict__ C, const float* __restrict__ bias,
    int K, long lda, long ldb, long ldc, float alpha, int zdiv,
    long sA1, long sA0, long sB1, long sB0, long sC1, long sC0,
    long sBias1, long sBias0) {
  constexpr int BK = 32;
  constexpr int WTM = BM / WM, WTN = BN / WN, MR = WTM / 16, NR = WTN / 16;
  constexpr int AISS = BM * BK / 2048;
  constexpr int BISS = BN * BK / 2048;
  __shared__ bf16 sa[BM * BK];
  __shared__ bf16 sb[BN * BK];
  const int nwg = gridDim.x * gridDim.y * gridDim.z;
  const int bid = blockIdx.x + gridDim.x * (blockIdx.y + gridDim.y * blockIdx.z);
  const int lid = xcd_swz(bid, nwg);
  const int bx = lid % gridDim.x;
  const int rem = lid / gridDim.x;
  const int by = rem % gridDim.y;
  const int z = rem / gridDim.y;
  const int zh = z / zdiv, zl = z - zh * zdiv;
  const bf16* Ab = A + zh * sA1 + zl * sA0 + (long)by * BM * lda;
  const bf16* Bb = Bp + zh * sB1 + zl * sB0 + (long)bx * BN * ldb;
  const int tid = threadIdx.x, lane = tid & 63, wid = tid >> 6;
  const int wm = wid / WN, wn = wid % WN;

  const int srow = tid >> 2;
  const int scol = (tid & 3) * 8;
  const bf16* aptr[AISS];
  bf16* aldst[AISS];
  #pragma unroll
  for (int i = 0; i < AISS; i++) {
    aptr[i] = Ab + (long)(srow + i * 64) * lda + scol;
    aldst[i] = &sa[i * 2048 + (wid << 9)];
  }
  const bf16* bptr[BISS];
  bf16* bldst[BISS];
  #pragma unroll
  for (int i = 0; i < BISS; i++) {
    bptr[i] = Bb + (long)(srow + i * 64) * ldb + scol;
    bldst[i] = &sb[i * 2048 + (wid << 9)];
  }

  f32x4 acc[MR][NR] = {};
  const int rA = wm * WTM + (lane & 15);
  const int rB = wn * WTN + (lane & 15);
  const int kk = (lane >> 4) * 8;

  for (int k0 = 0; k0 < K; k0 += BK) {
    #pragma unroll
    for (int i = 0; i < AISS; i++) GLOAD16(aptr[i] + k0, aldst[i]);
    #pragma unroll
    for (int i = 0; i < BISS; i++) GLOAD16(bptr[i] + k0, bldst[i]);
    __syncthreads();
    bf16x8 af[MR], bfr[NR];
    #pragma unroll
    for (int mi = 0; mi < MR; mi++) af[mi] = *(const bf16x8*)&sa[(rA + mi * 16) * BK + kk];
    #pragma unroll
    for (int ni = 0; ni < NR; ni++) bfr[ni] = *(const bf16x8*)&sb[(rB + ni * 16) * BK + kk];
    #pragma unroll
    for (int mi = 0; mi < MR; mi++)
      #pragma unroll
      for (int ni = 0; ni < NR; ni++)
        acc[mi][ni] = __builtin_amdgcn_mfma_f32_16x16x32_bf16(af[mi], bfr[ni], acc[mi][ni], 0, 0, 0);
    __syncthreads();
  }
  OutT* Cb = C + zh * sC1 + zl * sC0;
  const float* biasb = bias ? (bias + zh * sBias1 + zl * sBias0) : nullptr;
  const long rowBase = (long)by * BM + wm * WTM + ((lane >> 4) * 4);
  const long colBase = (long)bx * BN + wn * WTN + (lane & 15);
  #pragma unroll
  for (int mi = 0; mi < MR; mi++) {
    #pragma unroll
    for (int ni = 0; ni < NR; ni++) {
      long col = colBase + ni * 16;
      float bv = biasb ? biasb[col] : 0.f;
      #pragma unroll
      for (int r = 0; r < 4; r++) {
        long row = rowBase + mi * 16 + r;
        float v = acc[mi][ni][r] * alpha + bv;
        if (RELU) v = fmaxf(v, 0.f);
        Cb[row * ldc + col] = (OutT)v;
      }
    }
  }
}

// ---------------- 256^2 8-phase GEMM (T2 swizzle + T3/T4 counted vmcnt + T5) --
// C[M,N] = A[M,K] @ B[N,K]^T (+bias); BM=BN=256, BK=64, 512 thr (8 waves 2Mx4N).
// LDS 128 KiB: [2 buf][A 256x64 | B 256x64] bf16, swizzled:
//   phys_kbyte = logical_kbyte ^ ((row&7)<<4)  (involution; both sides).
// Prefetch tile t+2 into buf (t&1) during tile t's phases, into quarters
// already consumed: A-q{0,2}@P2, B-q{0,1}@P3, A-q{1,3}+B-q{2,3}@P4.
// vmcnt(8) once per tile (P4); vmcnt(0) at tile NT-2; raw s_barrier (no drain).
template <bool RELU, typename OutT>
__global__ __launch_bounds__(512, 2) void k_gemm8p(
    const bf16* __restrict__ A, const bf16* __restrict__ Bp,
    OutT* __restrict__ C, const float* __restrict__ bias,
    int K, long lda, long ldb, long ldc, int zdiv,
    long sA1, long sA0, long sB1, long sB0, long sC1, long sC0, long sBias1) {
  __shared__ bf16 smem[65536];   // 128 KiB
  const int nwg = gridDim.x * gridDim.y * gridDim.z;
  const int bid = blockIdx.x + gridDim.x * (blockIdx.y + gridDim.y * blockIdx.z);
  const int lid = xcd_swz(bid, nwg);
  const int bx = lid % gridDim.x;
  const int rem = lid / gridDim.x;
  const int by = rem % gridDim.y;
  const int z = rem / gridDim.y;
  const int zh = z / zdiv, zl = z - zh * zdiv;
  const bf16* Ab = A + zh * sA1 + zl * sA0 + (long)by * 256 * lda;
  const bf16* Bb = Bp + zh * sB1 + zl * sB0 + (long)bx * 256 * ldb;
  const int tid = threadIdx.x, lane = tid & 63, wid = tid >> 6;
  const int wm = wid >> 2, wn = wid & 3;
  const int lane15 = lane & 15, grp = lane >> 4;
  // staging: quarter q covers 64 rows; thread -> (row, k-chunk) with inverse swizzle
  const int s_r = (wid << 3) + (lane >> 3);            // 0..63 in quarter
  const int s_k = ((lane & 7) ^ (lane >> 3)) << 3;     // 0..56 elems
  const int ldst = wid << 9;                           // wave dest offset (elems)
  // frag-read swizzled inner byte offsets (within 128B row): for ks=0/1
  const int in0 = (grp << 4) ^ ((lane & 7) << 4);
  const int in1 = (64 | (grp << 4)) ^ ((lane & 7) << 4);

  const int NT = K >> 6;
  f32x4 acc[8][4] = {};
  bf16x8 a[4][2], b[2][2][2];

  auto stageA = [&](int q, long k0p, int cb) {
    GLOAD16(Ab + (long)((q << 6) + s_r) * lda + k0p + s_k, &smem[cb + (q << 12) + ldst]);
  };
  auto stageB = [&](int q, long k0p, int cb) {
    GLOAD16(Bb + (long)((q << 6) + s_r) * ldb + k0p + s_k, &smem[cb + 16384 + (q << 12) + ldst]);
  };
  auto loadA = [&](int mh, int cb) {
    #pragma unroll
    for (int mi2 = 0; mi2 < 4; mi2++) {
      int r = wm * 128 + mh * 64 + mi2 * 16 + lane15;
      a[mi2][0] = *(const bf16x8*)&smem[cb + (r << 6) + (in0 >> 1)];
      a[mi2][1] = *(const bf16x8*)&smem[cb + (r << 6) + (in1 >> 1)];
    }
  };
  auto loadB = [&](int nh, int cb) {
    #pragma unroll
    for (int ni2 = 0; ni2 < 2; ni2++) {
      int c = wn * 64 + nh * 32 + ni2 * 16 + lane15;
      b[nh][ni2][0] = *(const bf16x8*)&smem[cb + 16384 + (c << 6) + (in0 >> 1)];
      b[nh][ni2][1] = *(const bf16x8*)&smem[cb + 16384 + (c << 6) + (in1 >> 1)];
    }
  };
  auto mfmaQ = [&](int mh, int nh) {
    __builtin_amdgcn_s_setprio(1);
    #pragma unroll
    for (int ks = 0; ks < 2; ks++)
      #pragma unroll
      for (int mi2 = 0; mi2 < 4; mi2++)
        #pragma unroll
        for (int ni2 = 0; ni2 < 2; ni2++)
          acc[mh * 4 + mi2][nh * 2 + ni2] = __builtin_amdgcn_mfma_f32_16x16x32_bf16(
              a[mi2][ks], b[nh][ni2][ks], acc[mh * 4 + mi2][nh * 2 + ni2], 0, 0, 0);
    __builtin_amdgcn_s_setprio(0);
  };

  // prologue: stage tiles 0 (buf0) and 1 (buf1)
  #pragma unroll
  for (int q = 0; q < 4; q++) { stageA(q, 0, 0); stageB(q, 0, 0); }
  #pragma unroll
  for (int q = 0; q < 4; q++) { stageA(q, 64, 32768); stageB(q, 64, 32768); }
  asm volatile("s_waitcnt vmcnt(8)" ::: "memory");
  BAR();

  for (int t = 0; t < NT; t++) {
    const int cb = (t & 1) << 15;
    const long k0p = (long)(t + 2) << 6;
    const bool dostage = (t + 2) < NT;
    // P1: read A(mh=0), B(nh=0)
    loadA(0, cb); loadB(0, cb);
    BAR(); mfmaQ(0, 0); BAR();
    // P2: read B(nh=1); stage t+2 A-q0, A-q2
    loadB(1, cb);
    if (dostage) { stageA(0, k0p, cb); stageA(2, k0p, cb); }
    BAR(); mfmaQ(0, 1); BAR();
    // P3: read A(mh=1); stage t+2 B-q0, B-q1
    loadA(1, cb);
    if (dostage) { stageB(0, k0p, cb); stageB(1, k0p, cb); }
    BAR(); mfmaQ(1, 1); BAR();
    // P4: stage t+2 A-q1, A-q3, B-q2, B-q3; counted vmcnt
    if (dostage) {
      stageA(1, k0p, cb); stageA(3, k0p, cb);
      stageB(2, k0p, cb); stageB(3, k0p, cb);
      asm volatile("s_waitcnt vmcnt(8)" ::: "memory");
    } else if (t + 1 < NT) {
      asm volatile("s_waitcnt vmcnt(0)" ::: "memory");
    }
    BAR(); mfmaQ(1, 0); BAR();
  }

  OutT* Cb = C + zh * sC1 + zl * sC0;
  const float* biasb = bias ? (bias + zh * sBias1) : nullptr;
  const long rowBase = (long)by * 256 + wm * 128 + grp * 4;
  const long colBase = (long)bx * 256 + wn * 64 + lane15;
  #pragma unroll
  for (int mi = 0; mi < 8; mi++) {
    #pragma unroll
    for (int ni = 0; ni < 4; ni++) {
      long col = colBase + ni * 16;
      float bv = biasb ? biasb[col] : 0.f;
      #pragma unroll
      for (int r = 0; r < 4; r++) {
        long row = rowBase + mi * 16 + r;
        float v = acc[mi][ni][r] + bv;
        if (RELU) v = fmaxf(v, 0.f);
        Cb[row * ldc + col] = (OutT)v;
      }
    }
  }
}

// ---------------- fused flash attention ----------------
__global__ __launch_bounds__(256) void k_flash(
    const bf16* __restrict__ q, const bf16* __restrict__ kk,
    const bf16* __restrict__ vt, bf16* __restrict__ ao,
    long qrs, long krs) {
  __shared__ bf16 kt[2][2048];
  __shared__ bf16 vtt[2][2048];
  __shared__ bf16 p_lds[4][32 * 72];
  const int nwg = gridDim.x * gridDim.y;
  const int bid = blockIdx.x + gridDim.x * blockIdx.y;
  const int lid = xcd_swz(bid, nwg);
  const int qt = lid & 7;
  const int bh = lid >> 3;
  const int b = bh >> 4, h = bh & 15;
  const int tid = threadIdx.x, lane = tid & 63, wid = tid >> 6;
  const int colLane = lane & 15, grp = lane >> 4;
  const bf16* qb = q + (qrs >> 2) * b + h * 64;
  const bf16* kb = kk + (krs >> 2) * b + h * 64;
  const bf16* vb = vt + (long)bh * 65536;

  bf16x8 qf[2][2];
  const int qrow0 = qt * 128 + wid * 32 + colLane;
  #pragma unroll
  for (int mi = 0; mi < 2; mi++)
    #pragma unroll
    for (int ks = 0; ks < 2; ks++)
      qf[mi][ks] = *(const bf16x8*)&qb[(long)(qrow0 + mi * 16) * qrs + ks * 32 + grp * 8];

  const int srow = tid >> 2;
  const int scol = (tid & 3) * 8;

  f32x4 oacc[2][4] = {};
  float m_[2][4], l_[2][4];
  #pragma unroll
  for (int mi = 0; mi < 2; mi++)
    #pragma unroll
    for (int r = 0; r < 4; r++) { m_[mi][r] = -INFINITY; l_[mi][r] = 0.f; }
  bf16* pl = &p_lds[wid][0];

  for (int s0 = 0; s0 < 1024; s0 += 64) {
    GLOAD16(&kb[(long)(s0 + srow) * krs + scol], &kt[0][wid << 9]);
    GLOAD16(&kb[(long)(s0 + srow) * krs + 32 + scol], &kt[1][wid << 9]);
    GLOAD16(&vb[(long)srow * 1024 + s0 + scol], &vtt[0][wid << 9]);
    GLOAD16(&vb[(long)srow * 1024 + s0 + 32 + scol], &vtt[1][wid << 9]);
    __syncthreads();

    f32x4 sacc[2][4] = {};
    bf16x8 kf[4][2];
    #pragma unroll
    for (int ni = 0; ni < 4; ni++)
      #pragma unroll
      for (int ks = 0; ks < 2; ks++)
        kf[ni][ks] = *(const bf16x8*)&kt[ks][(colLane + ni * 16) * 32 + grp * 8];
    #pragma unroll
    for (int ks = 0; ks < 2; ks++)
      #pragma unroll
      for (int mi = 0; mi < 2; mi++)
        #pragma unroll
        for (int ni = 0; ni < 4; ni++)
          sacc[mi][ni] = __builtin_amdgcn_mfma_f32_16x16x32_bf16(qf[mi][ks], kf[ni][ks], sacc[mi][ni], 0, 0, 0);

    float mnew[2][4], sc[2][4], psum[2][4];
    #pragma unroll
    for (int mi = 0; mi < 2; mi++)
      #pragma unroll
      for (int r = 0; r < 4; r++) {
        float vx = fmaxf(fmaxf(sacc[mi][0][r], sacc[mi][1][r]),
                         fmaxf(sacc[mi][2][r], sacc[mi][3][r])) * 0.125f;
        #pragma unroll
        for (int o = 1; o < 16; o <<= 1) vx = fmaxf(vx, __shfl_xor(vx, o));
        float mn = fmaxf(m_[mi][r], vx);
        sc[mi][r] = __expf(m_[mi][r] - mn);
        m_[mi][r] = mn; mnew[mi][r] = mn;
        l_[mi][r] *= sc[mi][r];
        psum[mi][r] = 0.f;
      }
    #pragma unroll
    for (int mi = 0; mi < 2; mi++)
      #pragma unroll
      for (int ni = 0; ni < 4; ni++)
        #pragma unroll
        for (int r = 0; r < 4; r++)
          oacc[mi][ni][r] *= sc[mi][r];
    #pragma unroll
    for (int mi = 0; mi < 2; mi++)
      #pragma unroll
      for (int ni = 0; ni < 4; ni++)
        #pragma unroll
        for (int r = 0; r < 4; r++) {
          float p = __expf(sacc[mi][ni][r] * 0.125f - mnew[mi][r]);
          psum[mi][r] += p;
          pl[(mi * 16 + grp * 4 + r) * 72 + ni * 16 + colLane] = (bf16)p;
        }
    #pragma unroll
    for (int mi = 0; mi < 2; mi++)
      #pragma unroll
      for (int r = 0; r < 4; r++) {
        float ps = psum[mi][r];
        #pragma unroll
        for (int o = 1; o < 16; o <<= 1) ps += __shfl_xor(ps, o);
        l_[mi][r] += ps;
      }

    bf16x8 pa[2][2], vf[4][2];
    #pragma unroll
    for (int mi = 0; mi < 2; mi++)
      #pragma unroll
      for (int ks = 0; ks < 2; ks++)
        pa[mi][ks] = *(const bf16x8*)&pl[(colLane + mi * 16) * 72 + ks * 32 + grp * 8];
    #pragma unroll
    for (int ni = 0; ni < 4; ni++)
      #pragma unroll
      for (int ks = 0; ks < 2; ks++)
        vf[ni][ks] = *(const bf16x8*)&vtt[ks][(colLane + ni * 16) * 32 + grp * 8];
    #pragma unroll
    for (int ks = 0; ks < 2; ks++)
      #pragma unroll
      for (int mi = 0; mi < 2; mi++)
        #pragma unroll
        for (int ni = 0; ni < 4; ni++)
          oacc[mi][ni] = __builtin_amdgcn_mfma_f32_16x16x32_bf16(pa[mi][ks], vf[ni][ks], oacc[mi][ni], 0, 0, 0);
    __syncthreads();
  }

  #pragma unroll
  for (int mi = 0; mi < 2; mi++)
    #pragma unroll
    for (int r = 0; r < 4; r++) {
      float inv = 1.f / l_[mi][r];
      int t = qt * 128 + wid * 32 + mi * 16 + grp * 4 + r;
      long n = (long)t * 4 + b;
      #pragma unroll
      for (int ni = 0; ni < 4; ni++)
        ao[n * 1024 + h * 64 + ni * 16 + colLane] = (bf16)(oacc[mi][ni][r] * inv);
    }
}

// ---------------- residual add + LayerNorm ----------------
__global__ __launch_bounds__(256) void k_add_ln(const float* __restrict__ a, const float* __restrict__ b,
                                                const float* __restrict__ g, const float* __restrict__ be,
                                                float* __restrict__ out, bf16* __restrict__ outb) {
  long row = blockIdx.x;
  int tid = threadIdx.x;
  const float* pa = a + row * 1024;
  const float* pb = b + row * 1024;
  float v[4];
  float s = 0.f, sq = 0.f;
  #pragma unroll
  for (int i = 0; i < 4; i++) {
    int c = tid + i * 256;
    float x = pa[c] + pb[c];
    v[i] = x; s += x; sq += x * x;
  }
  #pragma unroll
  for (int o = 32; o; o >>= 1) { s += __shfl_xor(s, o); sq += __shfl_xor(sq, o); }
  __shared__ float r1[4], r2[4];
  int wid = tid >> 6;
  if ((tid & 63) == 0) { r1[wid] = s; r2[wid] = sq; }
  __syncthreads();
  s = r1[0] + r1[1] + r1[2] + r1[3];
  sq = r2[0] + r2[1] + r2[2] + r2[3];
  float mu = s * (1.f / 1024.f);
  float var = sq * (1.f / 1024.f) - mu * mu;
  float rstd = rsqrtf(var + 1e-5f);
  #pragma unroll
  for (int i = 0; i < 4; i++) {
    int c = tid + i * 256;
    float y = (v[i] - mu) * rstd * g[c] + be[c];
    out[row * 1024 + c] = y;
    if (outb) outb[row * 1024 + c] = (bf16)y;
  }
}

// ---------------- MoE gating ----------------
__global__ __launch_bounds__(256) void k_gate(const float* __restrict__ x, const float* __restrict__ wg,
                                              int* __restrict__ e1, int* __restrict__ e2,
                                              float* __restrict__ g1, float* __restrict__ g2) {
  int n = blockIdx.x * 4 + (threadIdx.x >> 6);
  int lane = threadIdx.x & 63;
  const float* xr = x + (long)n * 1024;
  float acc[8] = {0.f, 0.f, 0.f, 0.f, 0.f, 0.f, 0.f, 0.f};
  for (int i = 0; i < 16; i++) {
    float xv = xr[i * 64 + lane];
    const float* wr = wg + (long)(i * 64 + lane) * 8;
    #pragma unroll
    for (int e = 0; e < 8; e++) acc[e] += xv * wr[e];
  }
  #pragma unroll
  for (int e = 0; e < 8; e++)
    #pragma unroll
    for (int o = 32; o; o >>= 1) acc[e] += __shfl_xor(acc[e], o);
  if (lane == 0) {
    int i1 = 0; float b1v = acc[0];
    #pragma unroll
    for (int e = 1; e < 8; e++) if (acc[e] > b1v) { b1v = acc[e]; i1 = e; }
    int i2 = -1; float b2v = -INFINITY;
    #pragma unroll
    for (int e = 0; e < 8; e++) if (e != i1 && acc[e] > b2v) { b2v = acc[e]; i2 = e; }
    float den = 0.f;
    #pragma unroll
    for (int e = 0; e < 8; e++) den += __expf(acc[e] - b1v);
    float gg1 = 1.f / den;
    float gg2 = __expf(b2v - b1v) / den;
    float dn = gg1 + gg2 + 1e-9f;
    e1[n] = i1; e2[n] = i2; g1[n] = gg1 / dn; g2[n] = gg2 / dn;
  }
}

// ---------------- capacity positions, single wave ----------------
__global__ __launch_bounds__(64) void k_positions(const int* __restrict__ e1, const int* __restrict__ e2,
                                                  const float* __restrict__ g1, const float* __restrict__ g2,
                                                  int* __restrict__ d1, int* __restrict__ d2,
                                                  float* __restrict__ s1, float* __restrict__ s2,
                                                  int* __restrict__ p2t) {
  const int lane = threadIdx.x;
  int base1[8] = {0, 0, 0, 0, 0, 0, 0, 0};
  int base2[8] = {0, 0, 0, 0, 0, 0, 0, 0};
  const unsigned long long lt = (1ull << lane) - 1ull;
  int na = e1[lane], nb = e2[lane];
  for (int c = 0; c < 64; c++) {
    int a = na, b = nb;
    if (c < 63) { na = e1[(c + 1) * 64 + lane]; nb = e2[(c + 1) * 64 + lane]; }
    int n = c * 64 + lane;
    int pa = 0, pb = 0;
    #pragma unroll
    for (int e = 0; e < 8; e++) {
      unsigned long long ba = __ballot(a == e);
      unsigned long long bb = __ballot(b == e);
      if (a == e) pa = base1[e] + __popcll(ba & lt);
      if (b == e) pb = base2[e] + __popcll(bb & lt);
      base1[e] += __popcll(ba);
      base2[e] += __popcll(bb);
    }
    d1[n] = a * CAP_ + (pa < CAP_ ? pa : CAP_ - 1);
    s1[n] = (pa < CAP_) ? g1[n] : 0.f;
    p2t[n] = pb;
  }
  __shared__ int c1[8];
  if (lane == 0) {
    c1[0] = base1[0]; c1[1] = base1[1]; c1[2] = base1[2]; c1[3] = base1[3];
    c1[4] = base1[4]; c1[5] = base1[5]; c1[6] = base1[6]; c1[7] = base1[7];
  }
  __syncthreads();
  for (int c = 0; c < 64; c++) {
    int n = c * 64 + lane;
    int b = e2[n];
    int pb = p2t[n] + c1[b];
    d2[n] = b * CAP_ + (pb < CAP_ ? pb : CAP_ - 1);
    s2[n] = (pb < CAP_) ? g2[n] : 0.f;
  }
}

// ---------------- scatter tokens into expert buffers ----------------
__global__ __launch_bounds__(256) void k_scatter(const float* __restrict__ x, const int* __restrict__ d1,
                                                 const int* __restrict__ d2, const float* __restrict__ s1,
                                                 const float* __restrict__ s2, bf16* __restrict__ buf) {
  int n = blockIdx.x;
  int tid = threadIdx.x;
  const float* xr = x + (long)n * 1024;
  float v[4];
  #pragma unroll
  for (int i = 0; i < 4; i++) v[i] = xr[tid + i * 256];
  if (s1[n] != 0.f) {
    bf16* o = buf + (long)d1[n] * 1024;
    #pragma unroll
    for (int i = 0; i < 4; i++) o[tid + i * 256] = (bf16)v[i];
  }
  if (s2[n] != 0.f) {
    bf16* o = buf + (long)d2[n] * 1024;
    #pragma unroll
    for (int i = 0; i < 4; i++) o[tid + i * 256] = (bf16)v[i];
  }
}

// ---------------- gather expert outputs (2 split-K partials + b2) + LN3 ------
__global__ __launch_bounds__(256) void k_gather_ln(const float* __restrict__ x,
                                                   const float* __restrict__ p0, const float* __restrict__ p1,
                                                   const float* __restrict__ b2,
                                                   const int* __restrict__ d1, const int* __restrict__ d2,
                                                   const float* __restrict__ s1, const float* __restrict__ s2,
                                                   const float* __restrict__ g, const float* __restrict__ be,
                                                   float* __restrict__ out) {
  long n = blockIdx.x;
  int tid = threadIdx.x;
  float a1 = s1[n], a2 = s2[n];
  long i1 = (long)d1[n] * 1024, i2 = (long)d2[n] * 1024;
  long e1b = (long)(d1[n] >> 10) * 1024, e2b = (long)(d2[n] >> 10) * 1024;
  const float* xr = x + n * 1024;
  float v[4];
  float s = 0.f, sq = 0.f;
  #pragma unroll
  for (int i = 0; i < 4; i++) {
    int c = tid + i * 256;
    float r1v = p0[i1 + c] + p1[i1 + c] + b2[e1b + c];
    float r2v = p0[i2 + c] + p1[i2 + c] + b2[e2b + c];
    float y = xr[c] + a1 * r1v + a2 * r2v;
    v[i] = y; s += y; sq += y * y;
  }
  #pragma unroll
  for (int o = 32; o; o >>= 1) { s += __shfl_xor(s, o); sq += __shfl_xor(sq, o); }
  __shared__ float r1[4], r2[4];
  int wid = tid >> 6;
  if ((tid & 63) == 0) { r1[wid] = s; r2[wid] = sq; }
  __syncthreads();
  s = r1[0] + r1[1] + r1[2] + r1[3];
  sq = r2[0] + r2[1] + r2[2] + r2[3];
  float mu = s * (1.f / 1024.f);
  float var = sq * (1.f / 1024.f) - mu * mu;
  float rstd = rsqrtf(var + 1e-5f);
  #pragma unroll
  for (int i = 0; i < 4; i++) {
    int c = tid + i * 256;
    out[n * 1024 + c] = (v[i] - mu) * rstd * g[c] + be[c];
  }
}

// ---------------------------------------------------------------------------
extern "C" void kernel_launch(void* const* d_in, const int* in_sizes, int n_in,
                              void* d_out, int out_size, void* d_ws, size_t ws_size,
                              hipStream_t stream) {
  const float* tgt      = (const float*)d_in[0];
  const float* memory   = (const float*)d_in[1];
  const float* sa_in_w  = (const float*)d_in[2];
  const float* sa_in_b  = (const float*)d_in[3];
  const float* sa_out_w = (const float*)d_in[4];
  const float* sa_out_b = (const float*)d_in[5];
  const float* ca_in_w  = (const float*)d_in[6];
  const float* ca_in_b  = (const float*)d_in[7];
  const float* ca_out_w = (const float*)d_in[8];
  const float* ca_out_b = (const float*)d_in[9];
  const float* ln1_g    = (const float*)d_in[10];
  const float* ln1_b    = (const float*)d_in[11];
  const float* ln2_g    = (const float*)d_in[12];
  const float* ln2_b    = (const float*)d_in[13];
  const float* ln3_g    = (const float*)d_in[14];
  const float* ln3_b    = (const float*)d_in[15];
  const float* wg       = (const float*)d_in[16];
  const float* w1       = (const float*)d_in[17];
  const float* b1       = (const float*)d_in[18];
  const float* w2       = (const float*)d_in[19];
  const float* b2       = (const float*)d_in[20];

  char* ws = (char*)d_ws;
  auto B16 = [&](long o) { return (bf16*)(ws + o); };
  auto F32 = [&](long o) { return (float*)(ws + o); };
  auto I32 = [&](long o) { return (int*)(ws + o); };

  const dim3 blk256(256), blk512(512), blkT16(16, 16), blkT(64, 4);

  // ---- phase 0: conversions to bf16
  k_f32_to_bf16<<<3072, blk256, 0, stream>>>(sa_in_w, B16(OFF_WSAIN), 3072L * 1024 / 4);
  k_f32_to_bf16<<<1024, blk256, 0, stream>>>(sa_out_w, B16(OFF_WSAOUT), 1024L * 1024 / 4);
  k_f32_to_bf16<<<3072, blk256, 0, stream>>>(ca_in_w, B16(OFF_WCAIN), 3072L * 1024 / 4);
  k_f32_to_bf16<<<1024, blk256, 0, stream>>>(ca_out_w, B16(OFF_WCAOUT), 1024L * 1024 / 4);
  k_f32_to_bf16<<<4096, blk256, 0, stream>>>(tgt, B16(OFF_BTGT), 4096L * 1024 / 4);
  k_f32_to_bf16<<<4096, blk256, 0, stream>>>(memory, B16(OFF_BMEM), 4096L * 1024 / 4);

  // ---- phase 1: self-attention
  k_gemm_nt<128, 128, 2, 2, false, bf16><<<dim3(24, 32, 1), blk256, 0, stream>>>(
      B16(OFF_BTGT), B16(OFF_WSAIN), B16(OFF_QKV), sa_in_b,
      1024, 1024, 1024, 3072, 1.f, 1, 0, 0, 0, 0, 0, 0, 0, 0);
  k_extract_vt<<<dim3(1, 16, 64), blkT, 0, stream>>>(B16(OFF_QKV) + 2048, B16(OFF_VT), 12288, 3072);
  k_flash<<<dim3(8, 64), blk256, 0, stream>>>(
      B16(OFF_QKV), B16(OFF_QKV) + 1024, B16(OFF_VT), B16(OFF_AO), 12288, 12288);
  k_gemm_nt<128, 64, 4, 1, false, float><<<dim3(16, 32, 1), blk256, 0, stream>>>(
      B16(OFF_AO), B16(OFF_WSAOUT), F32(OFF_PROJ), sa_out_b,
      1024, 1024, 1024, 1024, 1.f, 1, 0, 0, 0, 0, 0, 0, 0, 0);
  k_add_ln<<<4096, blk256, 0, stream>>>(tgt, F32(OFF_PROJ), ln1_g, ln1_b, F32(OFF_X1), B16(OFF_BTGT));

  // ---- phase 2: cross-attention
  k_gemm_nt<128, 64, 4, 1, false, bf16><<<dim3(16, 32, 1), blk256, 0, stream>>>(
      B16(OFF_BTGT), B16(OFF_WCAIN), B16(OFF_QKV), ca_in_b,
      1024, 1024, 1024, 1024, 1.f, 1, 0, 0, 0, 0, 0, 0, 0, 0);
  k_gemm_nt<128, 64, 4, 1, false, bf16><<<dim3(32, 32, 1), blk256, 0, stream>>>(
      B16(OFF_BMEM), B16(OFF_WCAIN) + 1024L * 1024, B16(OFF_KVCA), ca_in_b + 1024,
      1024, 1024, 1024, 2048, 1.f, 1, 0, 0, 0, 0, 0, 0, 0, 0);
  k_extract_vt<<<dim3(1, 16, 64), blkT, 0, stream>>>(B16(OFF_KVCA) + 1024, B16(OFF_VT), 8192, 2048);
  k_flash<<<dim3(8, 64), blk256, 0, stream>>>(
      B16(OFF_QKV), B16(OFF_KVCA), B16(OFF_VT), B16(OFF_AO), 4096, 8192);
  k_gemm_nt<128, 64, 4, 1, false, float><<<dim3(16, 32, 1), blk256, 0, stream>>>(
      B16(OFF_AO), B16(OFF_WCAOUT), F32(OFF_PROJ), ca_out_b,
      1024, 1024, 1024, 1024, 1.f, 1, 0, 0, 0, 0, 0, 0, 0, 0);
  k_add_ln<<<4096, blk256, 0, stream>>>(F32(OFF_X1), F32(OFF_PROJ), ln2_g, ln2_b, F32(OFF_X2), (bf16*)nullptr);

  // ---- phase 3: MoE
  k_gate<<<1024, blk256, 0, stream>>>(F32(OFF_X2), wg, I32(OFF_E1), I32(OFF_E2), F32(OFF_G1), F32(OFF_G2));
  k_positions<<<1, 64, 0, stream>>>(I32(OFF_E1), I32(OFF_E2), F32(OFF_G1), F32(OFF_G2),
                                    I32(OFF_D1), I32(OFF_D2), F32(OFF_S1), F32(OFF_S2), I32(OFF_P2T));
  k_zero16<<<4096, blk256, 0, stream>>>((float4*)B16(OFF_QKV), 1048576L);
  k_scatter<<<4096, blk256, 0, stream>>>(F32(OFF_X2), I32(OFF_D1), I32(OFF_D2),
                                         F32(OFF_S1), F32(OFF_S2), B16(OFF_QKV));
  // w1t[e] = w1[e]^T : [4096][1024] bf16
  k_transpose_f32_bf16<<<dim3(64, 16, 8), blkT16, 0, stream>>>(w1, B16(OFF_SCORES), 1024, 4096);
  // h = relu(buf @ w1t^T + b1) : [8][1024][4096] bf16   (8-phase 256^2)
  k_gemm8p<true, bf16><<<dim3(16, 4, 8), blk512, 0, stream>>>(
      B16(OFF_QKV), B16(OFF_SCORES), B16(OFF_H), b1,
      1024, 1024, 1024, 4096, 1,
      1048576, 0, 4194304, 0, 4194304, 0, 4096);
  // w2t[e] = w2[e]^T : [1024][4096] bf16 (overwrite w1t)
  k_transpose_f32_bf16<<<dim3(16, 64, 8), blkT16, 0, stream>>>(w2, B16(OFF_SCORES), 4096, 1024);
  // eo = h @ w2t^T (split-K=2, no bias) -> partial0 @PROJ, partial1 @EO1  (8-phase)
  k_gemm8p<false, float><<<dim3(4, 4, 16), blk512, 0, stream>>>(
      B16(OFF_H), B16(OFF_SCORES), F32(OFF_PROJ), nullptr,
      2048, 4096, 4096, 1024, 2,
      4194304, 2048, 4194304, 2048, 1048576, (OFF_EO1 - OFF_PROJ) / 4, 0);
  // gather + b2 + residual + LN3 -> out
  k_gather_ln<<<4096, blk256, 0, stream>>>(F32(OFF_X2), F32(OFF_PROJ), F32(OFF_EO1), b2,
                                           I32(OFF_D1), I32(OFF_D2),
                                           F32(OFF_S1), F32(OFF_S2), ln3_g, ln3_b, (float*)d_out);

  (void)in_sizes; (void)n_in; (void)out_size; (void)ws_size;
}